// Round 7
// baseline (1264.210 us; speedup 1.0000x reference)
//
#include <hip/hip_runtime.h>
#include <stdint.h>

// LSTM autoencoder: B=256,T=256,D=128,H=256, gate order i,f,g,o.
// R1: persistent recurrence, full on-chip weight residency, double-buffered h.
// R2: perm fix for 8-wave dec.
// R3: pre-swizzled xp (coalesced dwordx4 reload in place), cvt_pk.
// R4/R5: enc recurrence 2 waves/SIMD (8 waves, NMT=8, NQ=2); 44 reg + 18 LDS + 2
//     L1-resident global frags; streamed Bh; per-phase xp chunk reload.
// R6: conflict-free frag-order h layout (bank conflicts 4.19M -> 0); acc init from xp;
//     xp reload before MFMA; setprio around MFMA.
// R7/R8: enc phase-merge + DPP lane-packing (row_shr:8), gates once on 64 live lanes.
// R9: (a) dec recurrence latency-hiding: GRP=2 batch-slices per 1024-thread wg
//     (16 waves = 4 waves/SIMD, grid 16). Each group has its own h double-buffer;
//     wg barrier syncs both (symmetric lockstep, correct & cheap). Dec step was
//     latency-bound (~2400cyc vs ~900 issue) -> chains of 2 groups interleave.
//     (b) k_xproj grid swapped n-fastest so consecutive wgs reuse one A-block from
//     L2/L3 instead of re-streaming A per n-sweep (xpE: 268MB -> ~17MB A traffic).

#define B_N 256
#define T_N 256
#define D_N 128
#define H_N 256

typedef __attribute__((ext_vector_type(8))) short bf16x8;  // MFMA A/B frag (4 VGPRs)
typedef __attribute__((ext_vector_type(4))) float f32x4;   // MFMA C/D frag
typedef unsigned short u16;
typedef unsigned int u32;
typedef __attribute__((ext_vector_type(4))) u32 u32v4;     // builtin vec: volatile-loadable

__device__ __forceinline__ float bflo(u32 u){ return __uint_as_float(u << 16); }
__device__ __forceinline__ float bfhi(u32 u){ return __uint_as_float(u & 0xffff0000u); }
__device__ __forceinline__ u32 f2bf_bits(float f){ u32 u = __float_as_uint(f); return (u + 0x7fffu + ((u >> 16) & 1u)) >> 16; }
__device__ __forceinline__ u32 pack2(float lo, float hi){ return f2bf_bits(lo) | (f2bf_bits(hi) << 16); }
__device__ __forceinline__ u32 cvtpk(float lo, float hi){ u32 r; asm("v_cvt_pk_bf16_f32 %0, %1, %2" : "=v"(r) : "v"(lo), "v"(hi)); return r; }
__device__ __forceinline__ float sigm(float x){ return __builtin_amdgcn_rcpf(1.f + __expf(-x)); }
__device__ __forceinline__ float tanh_f(float x){ return 1.f - 2.f * __builtin_amdgcn_rcpf(1.f + __expf(2.f * x)); }
// lanes lb>=8 <- src lanes lb-8 (row_shr:8, within 16-lane rows); lanes lb<8 keep 'old'
__device__ __forceinline__ float pack_hi(float oldv, float srcv){
  return __uint_as_float((u32)__builtin_amdgcn_update_dpp(
      (int)__float_as_uint(oldv), (int)__float_as_uint(srcv),
      0x118 /*row_shr:8*/, 0xF /*row_mask*/, 0xC /*bank_mask: lanes 8..15*/, false));
}

// ---------- prep kernels ----------
__global__ void k_cvt(const float* __restrict__ src, u16* __restrict__ dst, int n){
  int i = (blockIdx.x * blockDim.x + threadIdx.x) * 4;
  if (i >= n) return;
  float4 v = *(const float4*)(src + i);
  uint2 o; o.x = pack2(v.x, v.y); o.y = pack2(v.z, v.w);
  *(uint2*)(dst + i) = o;
}

// Row permutation p -> orig so that wave v (of 1<<VB waves) owns rows
// [v*4U,(v+1)*4U) = {i,f,g,o} x units[v*U,(v+1)*U), U = 1<<UB units/wave.
// p = (v << (UB+2)) | (g << UB) | uo  ;  orig = (g << (UB+VB)) | (v << UB) | uo
__global__ void k_permW(const float* __restrict__ W, u16* __restrict__ Wp, int K, int UB, int VB){
  int p = blockIdx.x;
  int uo = p & ((1 << UB) - 1), g = (p >> UB) & 3, v = p >> (UB + 2);
  int orig = (g << (UB + VB)) | (v << UB) | uo;
  for (int k = threadIdx.x; k < K; k += blockDim.x)
    Wp[(size_t)p * K + k] = (u16)f2bf_bits(W[(size_t)orig * K + k]);
}

__global__ void k_permB(const float* __restrict__ b1, const float* __restrict__ b2,
                        float* __restrict__ bp, int P, int UB, int VB){
  for (int p = threadIdx.x; p < P; p += blockDim.x){
    int uo = p & ((1 << UB) - 1), g = (p >> UB) & 3, v = p >> (UB + 2);
    int orig = (g << (UB + VB)) | (v << UB) | uo;
    bp[p] = b1[orig] + b2[orig];
  }
}

// ---------- input-projection GEMM: out[m,n] = sum_k A[m,k]*W[n,k] + bias[n] ----------
// Output layout (consumed by k_rec): with n=p -> wv=p>>(UB+2), g=(p>>UB)&3,
// q=(p&mask)>>4, u=p&15, qg=q*4+g, ch=qg>>1, half=qg&1:
// u16 idx = t*TS + (b>>3)*WS + wv*VS + ch*256 + (u>>2)*64 + (b&7)*8 + half*4 + (u&3).
// Phase q of k_rec consumes exactly chunks {2q, 2q+1}.
// Grid is (n-blocks, m-blocks) with n on blockIdx.x: consecutive wgs share one
// A-block -> A read once per m-block from L2/L3 (was re-streamed per n-sweep).
template<int KTOT, bool ENC_MAP, int UB, int VB>
__global__ __launch_bounds__(256, 1) void k_xproj(const u16* __restrict__ A, const u16* __restrict__ W,
                                                  const float* __restrict__ bias, u16* __restrict__ outp){
  constexpr int NQ  = 1 << (UB - 4);
  constexpr int NCH = 2 * NQ;
  constexpr size_t VS = (size_t)NCH * 256;
  constexpr size_t WS = (size_t)(1 << VB) * VS;
  constexpr size_t TS = 32 * WS;
  __shared__ u16 As[64][72];
  __shared__ u16 Ws[64][72];
  const int tid = threadIdx.x, l = tid & 63, v = tid >> 6;
  const int lb = l & 15, lq = l >> 4;
  const int m0 = blockIdx.y * 64, n0 = blockIdx.x * 64;
  f32x4 acc[4];
#pragma unroll
  for (int nt = 0; nt < 4; nt++){ float bv = bias[n0 + nt * 16 + lb]; f32x4 t = {bv, bv, bv, bv}; acc[nt] = t; }
  const int r = tid >> 3, c8 = (tid & 7) * 8;
  for (int kb = 0; kb < KTOT / 64; ++kb){
    __syncthreads();
    *(bf16x8*)&As[r][c8]      = *(const bf16x8*)&A[(size_t)(m0 + r) * KTOT + kb * 64 + c8];
    *(bf16x8*)&As[r + 32][c8] = *(const bf16x8*)&A[(size_t)(m0 + r + 32) * KTOT + kb * 64 + c8];
    *(bf16x8*)&Ws[r][c8]      = *(const bf16x8*)&W[(size_t)(n0 + r) * KTOT + kb * 64 + c8];
    *(bf16x8*)&Ws[r + 32][c8] = *(const bf16x8*)&W[(size_t)(n0 + r + 32) * KTOT + kb * 64 + c8];
    __syncthreads();
#pragma unroll
    for (int kc = 0; kc < 2; kc++){
      bf16x8 af = *(const bf16x8*)&As[v * 16 + lb][kc * 32 + lq * 8];
#pragma unroll
      for (int nt = 0; nt < 4; nt++){
        bf16x8 wf = *(const bf16x8*)&Ws[nt * 16 + lb][kc * 32 + lq * 8];
        acc[nt] = __builtin_amdgcn_mfma_f32_16x16x32_bf16(af, wf, acc[nt], 0, 0, 0);
      }
    }
  }
#pragma unroll
  for (int nt = 0; nt < 4; nt++){
    const int n  = n0 + nt * 16 + lb;
    const int wv = n >> (UB + 2);
    const int g  = (n >> UB) & 3;
    const int w  = n & ((1 << UB) - 1);
    const int q  = w >> 4;
    const int u  = w & 15;
    const int qg = q * 4 + g;
    const size_t nbase = (size_t)wv * VS + (size_t)(qg >> 1) * 256 + (size_t)(u >> 2) * 64
                       + (size_t)(qg & 1) * 4 + (size_t)(u & 3);
#pragma unroll
    for (int j = 0; j < 4; j += 2){
      const u32 pk = cvtpk(acc[nt][j], acc[nt][j + 1]);
#pragma unroll
      for (int s = 0; s < 2; ++s){
        const int m = m0 + v * 16 + lq * 4 + j + s;
        const int t = ENC_MAP ? (m & 255) : (m >> 8);
        const int b = ENC_MAP ? (m >> 8)  : (m & 255);
        outp[(size_t)t * TS + (size_t)(b >> 3) * WS + (size_t)(b & 7) * 8 + nbase]
            = (u16)(s ? (pk >> 16) : (pk & 0xffffu));
      }
    }
  }
}

// ---------- persistent recurrence ----------
// GRP independent batch-slices of 8 per wg (enc GRP=1 grid 32; dec GRP=2 grid 16,
// 1024 threads = 16 waves = 4 waves/SIMD for latency hiding). Each group owns its
// own h double-buffer; the single wg barrier syncs both groups (symmetric).
// Weights = A operand (M = gate rows, pre-permuted), h = B operand (N = batch,
// cols 8..15 dead). Wave v owns rows [v*NMT*16, (v+1)*NMT*16). Frag idx = kc*NMT+mt:
// [0,F_REG) regs, [F_REG,F_REG+F_LDS) per-wave LDS, rest volatile global (L1-hit).
// h stored in B-FRAGMENT ORDER: idx(b,k) = (k>>5)*512 + ((k>>3)&3)*128 + b*8 + (k&7);
// Bh read per kc = hrd[kc*512 + l*8]: contiguous 1KB, conflict-free.
// NQ==2 (enc): merged phases share Bh reads; DPP-packs ph1 into lanes lb>=8; gates
// once on 64 live lanes. NQ==1 (dec): per-phase path.
template<int KDIM, int NWAVE, int GRP, int NMT, int NKC, int NQ, int F_REG, int F_LDS, bool IS_DEC>
__global__ __launch_bounds__(NWAVE * GRP * 64, (NWAVE * GRP) / 4)
void k_rec(const u16* __restrict__ Wp, const u16* __restrict__ xp,
           u16* __restrict__ enc_out, float* __restrict__ out){
  constexpr int BUFS = NKC * 512;           // u16 per h buffer (frag-order layout)
  constexpr int NCH = 2 * NQ;
  constexpr size_t XSTR_T = (size_t)32 * NWAVE * NCH * 256;   // u16 per timestep
  static_assert(NMT == 4 * NQ, "tiles = 4 gates x NQ unit groups");
  static_assert(F_REG + F_LDS <= NMT * NKC, "reg+LDS tiers within total frags");
  extern __shared__ u16 smem[];
  const int tid = threadIdx.x, l = tid & 63;
  const int vg = tid >> 6;                   // 0..NWAVE*GRP-1
  const int grp = vg / NWAVE;
  const int v   = vg % NWAVE;
  u16* hbuf = smem + (size_t)grp * (2 * BUFS);         // [GRP][2][BUFS]
  u16* al   = smem + (size_t)GRP * (2 * BUFS);         // [NWAVE][F_LDS][512] (GRP==1 only)
  const int lb = l & 15, lq = l >> 4;
  const int slice = blockIdx.x * GRP + grp;  // 0..31 batch-slice-of-8 index
  const int b0 = slice * 8;
  const u16* wwave = Wp + (size_t)(v * (NMT * 16) + lb) * KDIM + lq * 8;
  u16* alw = al + (size_t)v * F_LDS * 512;

  // one-time weight load: frag layout A[m=lane&15][k=quad*8+j]
  bf16x8 Areg[(F_REG > 0) ? F_REG : 1];
#pragma unroll
  for (int kc = 0; kc < NKC; ++kc)
#pragma unroll
    for (int mt = 0; mt < NMT; ++mt){
      const int idx = kc * NMT + mt;
      const u16* src = wwave + (size_t)(mt * 16) * KDIM + kc * 32;
      if (idx < F_REG)              Areg[idx] = *(const bf16x8*)src;
      else if (idx < F_REG + F_LDS){ if (grp == 0) *(bf16x8*)&alw[(idx - F_REG) * 512 + l * 8] = *(const bf16x8*)src; }
      // idx >= F_REG+F_LDS: stays in global (L1-resident; read per step)
    }

  // xp lane base for this (slice, wave): chunk i at +i*256 u16 (coalesced 512B/chunk)
  const u16* xpl = xp + ((size_t)slice * NWAVE + v) * ((size_t)NCH * 256) + lq * 64 + lb * 8;
  uint4 xq[NCH] = {};
  if (lb < 8){
#pragma unroll
    for (int i = 0; i < NCH; ++i) xq[i] = *(const uint4*)(xpl + (size_t)i * 256);
  }

  for (int i = tid & (NWAVE * 64 - 1); i < 2 * BUFS; i += NWAVE * 64) hbuf[i] = 0; // h(-1)=0
  float c[4];
#pragma unroll
  for (int j = 0; j < 4; j++) c[j] = 0.f;
  __syncthreads();

  for (int t = 0; t < T_N; ++t){
    const u16* hrd = hbuf + (size_t)(t & 1) * BUFS;
    u16*       hwr = hbuf + (size_t)((t & 1) ^ 1) * BUFS;

    if constexpr (NQ == 2){
      // ----- merged 2-phase path (enc) -----
      f32x4 acc[2][4];
#pragma unroll
      for (int ph = 0; ph < 2; ++ph)
#pragma unroll
        for (int g = 0; g < 4; ++g){
          const int qg = ph * 4 + g;
          const uint4 cx = xq[qg >> 1];
          const u32 w0 = (qg & 1) ? cx.z : cx.x;
          const u32 w1 = (qg & 1) ? cx.w : cx.y;
          acc[ph][g][0] = bflo(w0); acc[ph][g][1] = bfhi(w0);
          acc[ph][g][2] = bflo(w1); acc[ph][g][3] = bfhi(w1);
        }
      // reload ALL chunks with t+1 data (full step + barrier of lead)
      if (t + 1 < T_N && lb < 8){
#pragma unroll
        for (int ch = 0; ch < NCH; ++ch)
          xq[ch] = *(const uint4*)(xpl + XSTR_T + (size_t)ch * 256);
      }
      __builtin_amdgcn_s_setprio(1);
#pragma unroll
      for (int kc = 0; kc < NKC; ++kc){
        const bf16x8 bh = *(const bf16x8*)&hrd[kc * 512 + l * 8];  // shared by both phases
#pragma unroll
        for (int ph = 0; ph < 2; ++ph)
#pragma unroll
          for (int g = 0; g < 4; ++g){
            const int idx = kc * NMT + g * NQ + ph;
            bf16x8 af;
            if (idx < F_REG)              af = Areg[idx];
            else if (idx < F_REG + F_LDS) af = *(const bf16x8*)&alw[(idx - F_REG) * 512 + l * 8];
            else {                         // L1-resident global tier; volatile defeats LICM
              const int mt = g * NQ + ph;
              u32v4 gw = *(const volatile u32v4*)(wwave + (size_t)(mt * 16) * KDIM + kc * 32);
              af = __builtin_bit_cast(bf16x8, gw);
            }
            acc[ph][g] = __builtin_amdgcn_mfma_f32_16x16x32_bf16(af, bh, acc[ph][g], 0, 0, 0);
          }
      }
      __builtin_amdgcn_s_setprio(0);
      // pack phase 1 (valid lanes lb<8) into phase 0's dead lanes (lb>=8): 16 DPP movs
      f32x4 comb[4];
#pragma unroll
      for (int g = 0; g < 4; ++g)
#pragma unroll
        for (int j = 0; j < 4; ++j)
          comb[g][j] = pack_hi(acc[0][g][j], acc[1][g][j]);
      // gates once on 64 fully-live lanes: (b = lb&7, phase = lb>>3)
      float hv[4];
#pragma unroll
      for (int j = 0; j < 4; ++j){
        float iv = sigm(comb[0][j]);
        float fv = sigm(comb[1][j]);
        float gv = tanh_f(comb[2][j]);
        float ov = sigm(comb[3][j]);
        float cc = fv * c[j] + iv * gv;
        c[j] = cc;
        hv[j] = ov * tanh_f(cc);
      }
      const int u0 = v * 32 + (lb >> 3) * 16 + lq * 4;
      const int widx = (u0 >> 5) * 512 + ((u0 >> 3) & 3) * 128 + (lb & 7) * 8 + (u0 & 7);
      uint2 hp; hp.x = cvtpk(hv[0], hv[1]); hp.y = cvtpk(hv[2], hv[3]);
      *(uint2*)&hwr[widx] = hp;
      __syncthreads();   // h(t) visible
      {
        const uint2 hs = *(const uint2*)&hwr[widx];
        *(uint2*)(enc_out + (size_t)(t * 256 + b0 + (lb & 7)) * KDIM + u0) = hs;
      }
    } else {
      // ----- single-phase path (dec) -----
      float4 osv[1];
      {
        const int q = 0;
        f32x4 acc[4];
#pragma unroll
        for (int g = 0; g < 4; ++g){
          const uint4 cx = xq[(q * 4 + g) >> 1];
          const u32 w0 = (g & 1) ? cx.z : cx.x;
          const u32 w1 = (g & 1) ? cx.w : cx.y;
          acc[g][0] = bflo(w0); acc[g][1] = bfhi(w0);
          acc[g][2] = bflo(w1); acc[g][3] = bfhi(w1);
        }
        if (t + 1 < T_N && lb < 8){
#pragma unroll
          for (int ch = 0; ch < NCH; ++ch)
            xq[ch] = *(const uint4*)(xpl + XSTR_T + (size_t)ch * 256);
        }
        __builtin_amdgcn_s_setprio(1);
#pragma unroll
        for (int kc = 0; kc < NKC; ++kc){
          const bf16x8 bh = *(const bf16x8*)&hrd[kc * 512 + l * 8];
#pragma unroll
          for (int g = 0; g < 4; ++g){
            const int idx = kc * NMT + g * NQ + q;
            bf16x8 af;
            if (idx < F_REG)              af = Areg[idx];
            else if (idx < F_REG + F_LDS) af = *(const bf16x8*)&alw[(idx - F_REG) * 512 + l * 8];
            else {
              const int mt = g * NQ + q;
              u32v4 gw = *(const volatile u32v4*)(wwave + (size_t)(mt * 16) * KDIM + kc * 32);
              af = __builtin_bit_cast(bf16x8, gw);
            }
            acc[g] = __builtin_amdgcn_mfma_f32_16x16x32_bf16(af, bh, acc[g], 0, 0, 0);
          }
        }
        __builtin_amdgcn_s_setprio(0);
        float hv[4];
#pragma unroll
        for (int j = 0; j < 4; ++j){
          float iv = sigm(acc[0][j]);
          float fv = sigm(acc[1][j]);
          float gv = tanh_f(acc[2][j]);
          float ov = sigm(acc[3][j]);
          float cc = fv * c[j] + iv * gv;
          c[j] = cc;
          hv[j] = ov * tanh_f(cc);
        }
        if (lb < 8){
          const int u0 = v * 16 + lq * 4;
          const int widx = (u0 >> 5) * 512 + ((u0 >> 3) & 3) * 128 + lb * 8 + (u0 & 7);
          uint2 hp; hp.x = cvtpk(hv[0], hv[1]); hp.y = cvtpk(hv[2], hv[3]);
          *(uint2*)&hwr[widx] = hp;
          osv[0] = make_float4(hv[0], hv[1], hv[2], hv[3]);
        }
      }
      __syncthreads();
      if (lb < 8){
        const int u0 = v * 16 + lq * 4;
        *(float4*)(out + ((size_t)(b0 + lb) * T_N + t) * D_N + u0) = osv[0];
      }
    }
    xpl += XSTR_T;
  }
}

extern "C" void kernel_launch(void* const* d_in, const int* in_sizes, int n_in,
                              void* d_out, int out_size, void* d_ws, size_t ws_size,
                              hipStream_t stream){
  const float* x    = (const float*)d_in[0];
  const float* eWih = (const float*)d_in[1];
  const float* eWhh = (const float*)d_in[2];
  const float* ebih = (const float*)d_in[3];
  const float* ebhh = (const float*)d_in[4];
  const float* dWih = (const float*)d_in[5];
  const float* dWhh = (const float*)d_in[6];
  const float* dbih = (const float*)d_in[7];
  const float* dbhh = (const float*)d_in[8];
  float* out = (float*)d_out;

  char* w = (char*)d_ws;
  size_t off = 0;
  auto carve = [&](size_t bytes) -> void* { void* p = w + off; off = (off + bytes + 255) & ~(size_t)255; return p; };
  u16*   xb    = (u16*)carve((size_t)B_N * T_N * D_N * 2);          // x in bf16
  u16*   WihEp = (u16*)carve((size_t)4 * H_N * D_N * 2);            // permuted enc Wih (UB=5,VB=3)
  u16*   WhhEp = (u16*)carve((size_t)4 * H_N * H_N * 2);            // permuted enc Whh (UB=5,VB=3)
  u16*   WihDp = (u16*)carve((size_t)4 * D_N * H_N * 2);            // permuted dec Wih (UB=4,VB=3)
  u16*   WhhDp = (u16*)carve((size_t)4 * D_N * D_N * 2);            // permuted dec Whh (UB=4,VB=3)
  float* bE    = (float*)carve((size_t)4 * H_N * 4);
  float* bD    = (float*)carve((size_t)4 * D_N * 4);
  u16*   xpE   = (u16*)carve((size_t)T_N * B_N * 4 * H_N * 2);      // swizzled [t][slice][v][ch][lq][bl][8]
  u16*   enc   = (u16*)carve((size_t)T_N * B_N * H_N * 2);          // encoded [T][B][H] bf16
  u16*   xpD   = (u16*)carve((size_t)T_N * B_N * 4 * D_N * 2);      // swizzled, dec
  (void)ws_size; (void)in_sizes; (void)n_in; (void)out_size;

  hipLaunchKernelGGL(k_cvt, dim3((B_N * T_N * D_N) / 1024), dim3(256), 0, stream, x, xb, B_N * T_N * D_N);
  hipLaunchKernelGGL(k_permW, dim3(1024), dim3(128), 0, stream, eWih, WihEp, 128, 5, 3);
  hipLaunchKernelGGL(k_permW, dim3(1024), dim3(128), 0, stream, eWhh, WhhEp, 256, 5, 3);
  hipLaunchKernelGGL(k_permW, dim3(512),  dim3(128), 0, stream, dWih, WihDp, 256, 4, 3);
  hipLaunchKernelGGL(k_permW, dim3(512),  dim3(128), 0, stream, dWhh, WhhDp, 128, 4, 3);
  hipLaunchKernelGGL(k_permB, dim3(1), dim3(256), 0, stream, ebih, ebhh, bE, 1024, 5, 3);
  hipLaunchKernelGGL(k_permB, dim3(1), dim3(256), 0, stream, dbih, dbhh, bD, 512, 4, 3);

  // enc x-proj: [65536,1024] = xb @ WihEp^T  (A rows m=b*T+t); n-fastest grid for A reuse
  hipLaunchKernelGGL((k_xproj<128, true, 5, 3>),  dim3(16, 1024), dim3(256), 0, stream, xb,  WihEp, bE, xpE);
  // enc recurrence: 8 waves (2/SIMD), 8 Mtiles x 8 kc, 44 reg + 18 LDS + 2 global frags
  // LDS: 2*8*512*2 + 8*18*1024 = 163840 B (exactly 160 KiB)
  hipLaunchKernelGGL((k_rec<256, 8, 1, 8, 8, 2, 44, 18, false>), dim3(32), dim3(512),
                     2 * 8 * 512 * 2 + 8 * 18 * 1024, stream, WhhEp, xpE, enc, (float*)nullptr);
  // dec x-proj: [65536,512] = enc @ WihDp^T (A rows m=t*B+b); n-fastest grid
  hipLaunchKernelGGL((k_xproj<256, false, 4, 3>), dim3(8, 1024),  dim3(256), 0, stream, enc, WihDp, bD, xpD);
  // dec recurrence: GRP=2 slices/wg, 16 waves (4/SIMD), grid 16; all 16 frags in regs
  // LDS: 2 * (2*4*512*2) = 16384 B
  hipLaunchKernelGGL((k_rec<128, 8, 2, 4, 4, 1, 16, 0, true>),  dim3(16), dim3(1024),
                     2 * (2 * 4 * 512 * 2), stream, WhhDp, xpD, (u16*)nullptr, out);
}

// Round 8
// 1051.208 us; speedup vs baseline: 1.2026x; 1.2026x over previous
//
#include <hip/hip_runtime.h>
#include <stdint.h>

// LSTM autoencoder: B=256,T=256,D=128,H=256, gate order i,f,g,o.
// R1: persistent recurrence, full on-chip weight residency, double-buffered h.
// R3: pre-swizzled xp (coalesced dwordx4 reload in place), cvt_pk.
// R4/R5: enc recurrence 2 waves/SIMD (8 waves, NMT=8, NQ=2); 44 reg + 18 LDS + 2
//     L1-resident global frags; streamed Bh; per-phase xp chunk reload.
// R6: conflict-free frag-order h layout; acc init from xp; setprio around MFMA.
// R7/R8: enc phase-merge + DPP lane-packing (row_shr:8), gates once on 64 live lanes.
// R9 (REVERTED): dec GRP=2 grid-16 and xproj n-fastest both regressed (+134us total);
//     dec and xproj restored to the measured R8 configuration.
// R10: enc batch-slice 8 -> SB=4 (grid 64 wgs = 64 CUs). Per-CU MFMA unchanged
//     (irreducible), per-CU gate VALU HALVED via double DPP pack:
//       (1) phase1 -> lanes 4..7   (row_shr:4  = 0x114, bank_mask 0x2)
//       (2) j{2,3} -> lanes 8..15  (row_shr:8  = 0x118, bank_mask 0xC)
//     -> all 64 lanes hold 2 h-values, gates run 2 iterations (trans 40->20/step).
//     xp layout parametrized by SB (chunk = SB*32 u16; T-stride SB-invariant).

#define B_N 256
#define T_N 256
#define D_N 128
#define H_N 256

typedef __attribute__((ext_vector_type(8))) short bf16x8;  // MFMA A/B frag (4 VGPRs)
typedef __attribute__((ext_vector_type(4))) float f32x4;   // MFMA C/D frag
typedef unsigned short u16;
typedef unsigned int u32;
typedef __attribute__((ext_vector_type(4))) u32 u32v4;     // builtin vec: volatile-loadable

__device__ __forceinline__ float bflo(u32 u){ return __uint_as_float(u << 16); }
__device__ __forceinline__ float bfhi(u32 u){ return __uint_as_float(u & 0xffff0000u); }
__device__ __forceinline__ u32 f2bf_bits(float f){ u32 u = __float_as_uint(f); return (u + 0x7fffu + ((u >> 16) & 1u)) >> 16; }
__device__ __forceinline__ u32 pack2(float lo, float hi){ return f2bf_bits(lo) | (f2bf_bits(hi) << 16); }
__device__ __forceinline__ u32 cvtpk(float lo, float hi){ u32 r; asm("v_cvt_pk_bf16_f32 %0, %1, %2" : "=v"(r) : "v"(lo), "v"(hi)); return r; }
__device__ __forceinline__ float sigm(float x){ return __builtin_amdgcn_rcpf(1.f + __expf(-x)); }
__device__ __forceinline__ float tanh_f(float x){ return 1.f - 2.f * __builtin_amdgcn_rcpf(1.f + __expf(2.f * x)); }
// generic DPP select: enabled dest lanes get src from (lane - shift) per CTRL; others keep old
template<int CTRL, int BANK>
__device__ __forceinline__ float pack_dpp(float oldv, float srcv){
  return __uint_as_float((u32)__builtin_amdgcn_update_dpp(
      (int)__float_as_uint(oldv), (int)__float_as_uint(srcv),
      CTRL, 0xF /*row_mask*/, BANK, false));
}

// ---------- prep kernels ----------
__global__ void k_cvt(const float* __restrict__ src, u16* __restrict__ dst, int n){
  int i = (blockIdx.x * blockDim.x + threadIdx.x) * 4;
  if (i >= n) return;
  float4 v = *(const float4*)(src + i);
  uint2 o; o.x = pack2(v.x, v.y); o.y = pack2(v.z, v.w);
  *(uint2*)(dst + i) = o;
}

// Row permutation p -> orig so that wave v (of 1<<VB waves) owns rows
// [v*4U,(v+1)*4U) = {i,f,g,o} x units[v*U,(v+1)*U), U = 1<<UB units/wave.
__global__ void k_permW(const float* __restrict__ W, u16* __restrict__ Wp, int K, int UB, int VB){
  int p = blockIdx.x;
  int uo = p & ((1 << UB) - 1), g = (p >> UB) & 3, v = p >> (UB + 2);
  int orig = (g << (UB + VB)) | (v << UB) | uo;
  for (int k = threadIdx.x; k < K; k += blockDim.x)
    Wp[(size_t)p * K + k] = (u16)f2bf_bits(W[(size_t)orig * K + k]);
}

__global__ void k_permB(const float* __restrict__ b1, const float* __restrict__ b2,
                        float* __restrict__ bp, int P, int UB, int VB){
  for (int p = threadIdx.x; p < P; p += blockDim.x){
    int uo = p & ((1 << UB) - 1), g = (p >> UB) & 3, v = p >> (UB + 2);
    int orig = (g << (UB + VB)) | (v << UB) | uo;
    bp[p] = b1[orig] + b2[orig];
  }
}

// ---------- input-projection GEMM: out[m,n] = sum_k A[m,k]*W[n,k] + bias[n] ----------
// Output layout (consumed by k_rec): with n=p -> wv=p>>(UB+2), g=(p>>UB)&3,
// q=(p&mask)>>4, u=p&15, qg=q*4+g, ch=qg>>1, half=qg&1, slice=b/SB, bl=b%SB:
// u16 idx = t*TS + slice*WS + wv*VS + ch*(SB*32) + (u>>2)*(SB*8) + bl*8 + half*4 + (u&3)
template<int KTOT, bool ENC_MAP, int UB, int VB, int SB>
__global__ __launch_bounds__(256, 1) void k_xproj(const u16* __restrict__ A, const u16* __restrict__ W,
                                                  const float* __restrict__ bias, u16* __restrict__ outp){
  constexpr int NQ  = 1 << (UB - 4);
  constexpr int NCH = 2 * NQ;
  constexpr size_t VS = (size_t)NCH * SB * 32;
  constexpr size_t WS = (size_t)(1 << VB) * VS;
  constexpr size_t TS = (size_t)(B_N / SB) * WS;
  __shared__ u16 As[64][72];
  __shared__ u16 Ws[64][72];
  const int tid = threadIdx.x, l = tid & 63, v = tid >> 6;
  const int lb = l & 15, lq = l >> 4;
  const int m0 = blockIdx.x * 64, n0 = blockIdx.y * 64;
  f32x4 acc[4];
#pragma unroll
  for (int nt = 0; nt < 4; nt++){ float bv = bias[n0 + nt * 16 + lb]; f32x4 t = {bv, bv, bv, bv}; acc[nt] = t; }
  const int r = tid >> 3, c8 = (tid & 7) * 8;
  for (int kb = 0; kb < KTOT / 64; ++kb){
    __syncthreads();
    *(bf16x8*)&As[r][c8]      = *(const bf16x8*)&A[(size_t)(m0 + r) * KTOT + kb * 64 + c8];
    *(bf16x8*)&As[r + 32][c8] = *(const bf16x8*)&A[(size_t)(m0 + r + 32) * KTOT + kb * 64 + c8];
    *(bf16x8*)&Ws[r][c8]      = *(const bf16x8*)&W[(size_t)(n0 + r) * KTOT + kb * 64 + c8];
    *(bf16x8*)&Ws[r + 32][c8] = *(const bf16x8*)&W[(size_t)(n0 + r + 32) * KTOT + kb * 64 + c8];
    __syncthreads();
#pragma unroll
    for (int kc = 0; kc < 2; kc++){
      bf16x8 af = *(const bf16x8*)&As[v * 16 + lb][kc * 32 + lq * 8];
#pragma unroll
      for (int nt = 0; nt < 4; nt++){
        bf16x8 wf = *(const bf16x8*)&Ws[nt * 16 + lb][kc * 32 + lq * 8];
        acc[nt] = __builtin_amdgcn_mfma_f32_16x16x32_bf16(af, wf, acc[nt], 0, 0, 0);
      }
    }
  }
#pragma unroll
  for (int nt = 0; nt < 4; nt++){
    const int n  = n0 + nt * 16 + lb;
    const int wv = n >> (UB + 2);
    const int g  = (n >> UB) & 3;
    const int w  = n & ((1 << UB) - 1);
    const int q  = w >> 4;
    const int u  = w & 15;
    const int qg = q * 4 + g;
    const size_t nbase = (size_t)wv * VS + (size_t)(qg >> 1) * (SB * 32) + (size_t)(u >> 2) * (SB * 8)
                       + (size_t)(qg & 1) * 4 + (size_t)(u & 3);
#pragma unroll
    for (int j = 0; j < 4; j += 2){
      const u32 pk = cvtpk(acc[nt][j], acc[nt][j + 1]);
#pragma unroll
      for (int s = 0; s < 2; ++s){
        const int m = m0 + v * 16 + lq * 4 + j + s;
        const int t = ENC_MAP ? (m & 255) : (m >> 8);
        const int b = ENC_MAP ? (m >> 8)  : (m & 255);
        outp[(size_t)t * TS + (size_t)(b / SB) * WS + (size_t)(b % SB) * 8 + nbase]
            = (u16)(s ? (pk >> 16) : (pk & 0xffffu));
      }
    }
  }
}

// ---------- persistent recurrence ----------
// Grid B_N/SB wgs; wg owns batch slice of SB. Weights = A operand (M = gate rows,
// pre-permuted), h = B operand (N = batch, cols SB..15 dead). Wave v owns rows
// [v*NMT*16, (v+1)*NMT*16). Frag idx = kc*NMT+mt: [0,F_REG) regs, [F_REG,F_REG+F_LDS)
// per-wave LDS, rest volatile global (L1-hit).
// h in B-FRAGMENT ORDER: idx(b,k) = (k>>5)*512 + ((k>>3)&3)*128 + b*8 + (k&7);
// Bh read per kc = hrd[kc*512 + l*8]: contiguous 1KB, conflict-free. ONE barrier/step.
// NQ==2 (enc): merged phases share Bh reads; DPP pack (SB=8: 1 stage; SB=4: 2 stages)
// fills all 64 lanes -> gates on 4 (SB=8) or 2 (SB=4) values/lane.
// NQ==1 (dec): per-phase path (SB=8).
template<int KDIM, int NWAVE, int SB, int NMT, int NKC, int NQ, int F_REG, int F_LDS, bool IS_DEC>
__global__ __launch_bounds__(NWAVE * 64, NWAVE / 4)
void k_rec(const u16* __restrict__ Wp, const u16* __restrict__ xp,
           u16* __restrict__ enc_out, float* __restrict__ out){
  constexpr int BUFS = NKC * 512;           // u16 per h buffer (frag-order layout)
  constexpr int NCH = 2 * NQ;
  constexpr int CHS = SB * 32;              // u16 per chunk
  constexpr size_t XSTR_T = (size_t)B_N * NWAVE * NCH * 32;   // u16 per timestep (SB-invariant)
  static_assert(NMT == 4 * NQ, "tiles = 4 gates x NQ unit groups");
  static_assert(F_REG + F_LDS <= NMT * NKC, "reg+LDS tiers within total frags");
  extern __shared__ u16 smem[];
  u16* hbuf = smem;                          // [2][BUFS]
  u16* al   = smem + 2 * BUFS;               // [NWAVE][F_LDS][512]
  const int tid = threadIdx.x, l = tid & 63, v = tid >> 6;
  const int lb = l & 15, lq = l >> 4;
  const int b0 = blockIdx.x * SB;
  const u16* wwave = Wp + (size_t)(v * (NMT * 16) + lb) * KDIM + lq * 8;
  u16* alw = al + (size_t)v * F_LDS * 512;

  // one-time weight load: frag layout A[m=lane&15][k=quad*8+j]
  bf16x8 Areg[(F_REG > 0) ? F_REG : 1];
#pragma unroll
  for (int kc = 0; kc < NKC; ++kc)
#pragma unroll
    for (int mt = 0; mt < NMT; ++mt){
      const int idx = kc * NMT + mt;
      const u16* src = wwave + (size_t)(mt * 16) * KDIM + kc * 32;
      if (idx < F_REG)              Areg[idx] = *(const bf16x8*)src;
      else if (idx < F_REG + F_LDS) *(bf16x8*)&alw[(idx - F_REG) * 512 + l * 8] = *(const bf16x8*)src;
      // idx >= F_REG+F_LDS: stays in global (L1-resident; read per step)
    }

  // xp lane base for this (slice, wave): chunk i at +i*CHS u16 (coalesced SB*64B/chunk)
  const u16* xpl = xp + ((size_t)blockIdx.x * NWAVE + v) * ((size_t)NCH * CHS) + lq * (SB * 8) + lb * 8;
  uint4 xq[NCH] = {};
  if (lb < SB){
#pragma unroll
    for (int i = 0; i < NCH; ++i) xq[i] = *(const uint4*)(xpl + (size_t)i * CHS);
  }

  for (int i = tid; i < 2 * BUFS; i += NWAVE * 64) hbuf[i] = 0;   // h(-1)=0 + dead b-slots
  float c[4];
#pragma unroll
  for (int j = 0; j < 4; j++) c[j] = 0.f;
  __syncthreads();

  for (int t = 0; t < T_N; ++t){
    const u16* hrd = hbuf + (size_t)(t & 1) * BUFS;
    u16*       hwr = hbuf + (size_t)((t & 1) ^ 1) * BUFS;

    if constexpr (NQ == 2){
      // ----- merged 2-phase path (enc) -----
      f32x4 acc[2][4];
#pragma unroll
      for (int ph = 0; ph < 2; ++ph)
#pragma unroll
        for (int g = 0; g < 4; ++g){
          const int qg = ph * 4 + g;
          const uint4 cx = xq[qg >> 1];
          const u32 w0 = (qg & 1) ? cx.z : cx.x;
          const u32 w1 = (qg & 1) ? cx.w : cx.y;
          acc[ph][g][0] = bflo(w0); acc[ph][g][1] = bfhi(w0);
          acc[ph][g][2] = bflo(w1); acc[ph][g][3] = bfhi(w1);
        }
      // reload ALL chunks with t+1 data (full step + barrier of lead)
      if (t + 1 < T_N && lb < SB){
#pragma unroll
        for (int ch = 0; ch < NCH; ++ch)
          xq[ch] = *(const uint4*)(xpl + XSTR_T + (size_t)ch * CHS);
      }
      __builtin_amdgcn_s_setprio(1);
#pragma unroll
      for (int kc = 0; kc < NKC; ++kc){
        const bf16x8 bh = *(const bf16x8*)&hrd[kc * 512 + l * 8];  // shared by both phases
#pragma unroll
        for (int ph = 0; ph < 2; ++ph)
#pragma unroll
          for (int g = 0; g < 4; ++g){
            const int idx = kc * NMT + g * NQ + ph;
            bf16x8 af;
            if (idx < F_REG)              af = Areg[idx];
            else if (idx < F_REG + F_LDS) af = *(const bf16x8*)&alw[(idx - F_REG) * 512 + l * 8];
            else {                         // L1-resident global tier; volatile defeats LICM
              const int mt = g * NQ + ph;
              u32v4 gw = *(const volatile u32v4*)(wwave + (size_t)(mt * 16) * KDIM + kc * 32);
              af = __builtin_bit_cast(bf16x8, gw);
            }
            acc[ph][g] = __builtin_amdgcn_mfma_f32_16x16x32_bf16(af, bh, acc[ph][g], 0, 0, 0);
          }
      }
      __builtin_amdgcn_s_setprio(0);
      if constexpr (SB == 8){
        // pack phase 1 (lanes lb<8) into lanes lb>=8; gates on 4 values/lane
        f32x4 comb[4];
#pragma unroll
        for (int g = 0; g < 4; ++g)
#pragma unroll
          for (int j = 0; j < 4; ++j)
            comb[g][j] = pack_dpp<0x118, 0xC>(acc[0][g][j], acc[1][g][j]);
        float hv[4];
#pragma unroll
        for (int j = 0; j < 4; ++j){
          float iv = sigm(comb[0][j]);
          float fv = sigm(comb[1][j]);
          float gv = tanh_f(comb[2][j]);
          float ov = sigm(comb[3][j]);
          float cc = fv * c[j] + iv * gv;
          c[j] = cc;
          hv[j] = ov * tanh_f(cc);
        }
        const int u0 = v * 32 + (lb >> 3) * 16 + lq * 4;
        const int widx = (u0 >> 5) * 512 + ((u0 >> 3) & 3) * 128 + (lb & 7) * 8 + (u0 & 7);
        uint2 hp; hp.x = cvtpk(hv[0], hv[1]); hp.y = cvtpk(hv[2], hv[3]);
        *(uint2*)&hwr[widx] = hp;
        __syncthreads();   // h(t) visible
        *(uint2*)(enc_out + (size_t)(t * 256 + b0 + (lb & 7)) * KDIM + u0) = hp;
      } else {
        // SB == 4: stage 1 pack phase1 (lanes 0..3) -> lanes 4..7
        f32x4 comb[4];
#pragma unroll
        for (int g = 0; g < 4; ++g)
#pragma unroll
          for (int j = 0; j < 4; ++j)
            comb[g][j] = pack_dpp<0x114, 0x2>(acc[0][g][j], acc[1][g][j]);
        // stage 2: pack j{2,3} (lanes 0..7) -> lanes 8..15; all 64 lanes live, 2 vals
        float fin[4][2];
#pragma unroll
        for (int g = 0; g < 4; ++g)
#pragma unroll
          for (int jj = 0; jj < 2; ++jj)
            fin[g][jj] = pack_dpp<0x118, 0xC>(comb[g][jj], comb[g][jj + 2]);
        float hv[2];
#pragma unroll
        for (int jj = 0; jj < 2; ++jj){
          float iv = sigm(fin[0][jj]);
          float fv = sigm(fin[1][jj]);
          float gv = tanh_f(fin[2][jj]);
          float ov = sigm(fin[3][jj]);
          float cc = fv * c[jj] + iv * gv;
          c[jj] = cc;
          hv[jj] = ov * tanh_f(cc);
        }
        // lane decode: b = lb&3, phase = (lb>>2)&1, j-half = lb>>3
        const int bq = lb & 3, ph = (lb >> 2) & 1, jh = lb >> 3;
        const int u0 = v * 32 + ph * 16 + lq * 4 + jh * 2;
        const int widx = (u0 >> 5) * 512 + ((u0 >> 3) & 3) * 128 + bq * 8 + (u0 & 7);
        const u32 hp = cvtpk(hv[0], hv[1]);
        *(u32*)&hwr[widx] = hp;
        __syncthreads();   // h(t) visible
        *(u32*)(enc_out + (size_t)(t * 256 + b0 + bq) * KDIM + u0) = hp;
      }
    } else {
      // ----- single-phase path (dec) -----
      float4 osv[1];
      {
        const int q = 0;
        f32x4 acc[4];
#pragma unroll
        for (int g = 0; g < 4; ++g){
          const uint4 cx = xq[(q * 4 + g) >> 1];
          const u32 w0 = (g & 1) ? cx.z : cx.x;
          const u32 w1 = (g & 1) ? cx.w : cx.y;
          acc[g][0] = bflo(w0); acc[g][1] = bfhi(w0);
          acc[g][2] = bflo(w1); acc[g][3] = bfhi(w1);
        }
        if (t + 1 < T_N && lb < SB){
#pragma unroll
          for (int ch = 0; ch < NCH; ++ch)
            xq[ch] = *(const uint4*)(xpl + XSTR_T + (size_t)ch * CHS);
        }
        __builtin_amdgcn_s_setprio(1);
#pragma unroll
        for (int kc = 0; kc < NKC; ++kc){
          const bf16x8 bh = *(const bf16x8*)&hrd[kc * 512 + l * 8];
#pragma unroll
          for (int g = 0; g < 4; ++g){
            const int idx = kc * NMT + g * NQ + q;
            bf16x8 af;
            if (idx < F_REG)              af = Areg[idx];
            else if (idx < F_REG + F_LDS) af = *(const bf16x8*)&alw[(idx - F_REG) * 512 + l * 8];
            else {
              const int mt = g * NQ + q;
              u32v4 gw = *(const volatile u32v4*)(wwave + (size_t)(mt * 16) * KDIM + kc * 32);
              af = __builtin_bit_cast(bf16x8, gw);
            }
            acc[g] = __builtin_amdgcn_mfma_f32_16x16x32_bf16(af, bh, acc[g], 0, 0, 0);
          }
        }
        __builtin_amdgcn_s_setprio(0);
        float hv[4];
#pragma unroll
        for (int j = 0; j < 4; ++j){
          float iv = sigm(acc[0][j]);
          float fv = sigm(acc[1][j]);
          float gv = tanh_f(acc[2][j]);
          float ov = sigm(acc[3][j]);
          float cc = fv * c[j] + iv * gv;
          c[j] = cc;
          hv[j] = ov * tanh_f(cc);
        }
        if (lb < SB){
          const int u0 = v * 16 + lq * 4;
          const int widx = (u0 >> 5) * 512 + ((u0 >> 3) & 3) * 128 + lb * 8 + (u0 & 7);
          uint2 hp; hp.x = cvtpk(hv[0], hv[1]); hp.y = cvtpk(hv[2], hv[3]);
          *(uint2*)&hwr[widx] = hp;
          osv[0] = make_float4(hv[0], hv[1], hv[2], hv[3]);
        }
      }
      __syncthreads();
      if (lb < SB){
        const int u0 = v * 16 + lq * 4;
        *(float4*)(out + ((size_t)(b0 + lb) * T_N + t) * D_N + u0) = osv[0];
      }
    }
    xpl += XSTR_T;
  }
}

extern "C" void kernel_launch(void* const* d_in, const int* in_sizes, int n_in,
                              void* d_out, int out_size, void* d_ws, size_t ws_size,
                              hipStream_t stream){
  const float* x    = (const float*)d_in[0];
  const float* eWih = (const float*)d_in[1];
  const float* eWhh = (const float*)d_in[2];
  const float* ebih = (const float*)d_in[3];
  const float* ebhh = (const float*)d_in[4];
  const float* dWih = (const float*)d_in[5];
  const float* dWhh = (const float*)d_in[6];
  const float* dbih = (const float*)d_in[7];
  const float* dbhh = (const float*)d_in[8];
  float* out = (float*)d_out;

  char* w = (char*)d_ws;
  size_t off = 0;
  auto carve = [&](size_t bytes) -> void* { void* p = w + off; off = (off + bytes + 255) & ~(size_t)255; return p; };
  u16*   xb    = (u16*)carve((size_t)B_N * T_N * D_N * 2);          // x in bf16
  u16*   WihEp = (u16*)carve((size_t)4 * H_N * D_N * 2);            // permuted enc Wih (UB=5,VB=3)
  u16*   WhhEp = (u16*)carve((size_t)4 * H_N * H_N * 2);            // permuted enc Whh (UB=5,VB=3)
  u16*   WihDp = (u16*)carve((size_t)4 * D_N * H_N * 2);            // permuted dec Wih (UB=4,VB=3)
  u16*   WhhDp = (u16*)carve((size_t)4 * D_N * D_N * 2);            // permuted dec Whh (UB=4,VB=3)
  float* bE    = (float*)carve((size_t)4 * H_N * 4);
  float* bD    = (float*)carve((size_t)4 * D_N * 4);
  u16*   xpE   = (u16*)carve((size_t)T_N * B_N * 4 * H_N * 2);      // swizzled [t][slice][v][ch][lq][bl][8]
  u16*   enc   = (u16*)carve((size_t)T_N * B_N * H_N * 2);          // encoded [T][B][H] bf16
  u16*   xpD   = (u16*)carve((size_t)T_N * B_N * 4 * D_N * 2);      // swizzled, dec
  (void)ws_size; (void)in_sizes; (void)n_in; (void)out_size;

  hipLaunchKernelGGL(k_cvt, dim3((B_N * T_N * D_N) / 1024), dim3(256), 0, stream, x, xb, B_N * T_N * D_N);
  hipLaunchKernelGGL(k_permW, dim3(1024), dim3(128), 0, stream, eWih, WihEp, 128, 5, 3);
  hipLaunchKernelGGL(k_permW, dim3(1024), dim3(128), 0, stream, eWhh, WhhEp, 256, 5, 3);
  hipLaunchKernelGGL(k_permW, dim3(512),  dim3(128), 0, stream, dWih, WihDp, 256, 4, 3);
  hipLaunchKernelGGL(k_permW, dim3(512),  dim3(128), 0, stream, dWhh, WhhDp, 128, 4, 3);
  hipLaunchKernelGGL(k_permB, dim3(1), dim3(256), 0, stream, ebih, ebhh, bE, 1024, 5, 3);
  hipLaunchKernelGGL(k_permB, dim3(1), dim3(256), 0, stream, dbih, dbhh, bD, 512, 4, 3);

  // enc x-proj: [65536,1024] = xb @ WihEp^T  (A rows m=b*T+t); SB=4 layout
  hipLaunchKernelGGL((k_xproj<128, true, 5, 3, 4>),  dim3(1024, 16), dim3(256), 0, stream, xb,  WihEp, bE, xpE);
  // enc recurrence: SB=4, 64 wgs, 8 waves (2/SIMD), 44 reg + 18 LDS + 2 global frags
  // LDS: 2*8*512*2 + 8*18*1024 = 163840 B (exactly 160 KiB)
  hipLaunchKernelGGL((k_rec<256, 8, 4, 8, 8, 2, 44, 18, false>), dim3(64), dim3(512),
                     2 * 8 * 512 * 2 + 8 * 18 * 1024, stream, WhhEp, xpE, enc, (float*)nullptr);
  // dec x-proj: [65536,512] = enc @ WihDp^T (A rows m=t*B+b); SB=8 layout
  hipLaunchKernelGGL((k_xproj<256, false, 4, 3, 8>), dim3(1024, 8),  dim3(256), 0, stream, enc, WihDp, bD, xpD);
  // dec recurrence: SB=8, 32 wgs, 8 waves (2/SIMD), all 16 frags in regs; fp32 out
  // LDS: 2*4*512*2 = 8192 B
  hipLaunchKernelGGL((k_rec<128, 8, 8, 4, 4, 1, 16, 0, true>),  dim3(32), dim3(512),
                     2 * 4 * 512 * 2, stream, WhhDp, xpD, (u16*)nullptr, out);
}

// Round 9
// 1009.711 us; speedup vs baseline: 1.2521x; 1.0411x over previous
//
#include <hip/hip_runtime.h>
#include <stdint.h>

// LSTM autoencoder: B=256,T=256,D=128,H=256, gate order i,f,g,o.
// R1: persistent recurrence, full on-chip weight residency, double-buffered h.
// R3: pre-swizzled xp (coalesced dwordx4 reload in place), cvt_pk.
// R4/R5: enc recurrence 2 waves/SIMD (8 waves, NMT=8, NQ=2); reg+LDS+global frag tiers;
//     streamed Bh; xp chunk reload in place.
// R6: conflict-free frag-order h layout; acc init from xp; setprio around MFMA.
// R7/R8: enc phase-merge + DPP lane-packing (row_shr:8), gates once on 64 live lanes.
// R10: enc SB=4 (64 wgs), double DPP pack (row_shr:4 bank2, row_shr:8 bankC) -> gates
//     2 iters; xp layout parametrized by SB. 533us enc, 1051 total.
// R11: (a) global-tier weight frags PREFETCHED at step start (were volatile-loaded in
//     the last kc iteration and consumed immediately -> ~300-400cyc un-hidden L1
//     latency per step on the critical path). (b) dec gate chain halved via the proven
//     row_shr:8/bankC pack: j{2,3} -> lanes 8..15, gates 2 iters, u32 h-write,
//     float2 out-store.

#define B_N 256
#define T_N 256
#define D_N 128
#define H_N 256

typedef __attribute__((ext_vector_type(8))) short bf16x8;  // MFMA A/B frag (4 VGPRs)
typedef __attribute__((ext_vector_type(4))) float f32x4;   // MFMA C/D frag
typedef unsigned short u16;
typedef unsigned int u32;
typedef __attribute__((ext_vector_type(4))) u32 u32v4;     // builtin vec: volatile-loadable

__device__ __forceinline__ float bflo(u32 u){ return __uint_as_float(u << 16); }
__device__ __forceinline__ float bfhi(u32 u){ return __uint_as_float(u & 0xffff0000u); }
__device__ __forceinline__ u32 f2bf_bits(float f){ u32 u = __float_as_uint(f); return (u + 0x7fffu + ((u >> 16) & 1u)) >> 16; }
__device__ __forceinline__ u32 pack2(float lo, float hi){ return f2bf_bits(lo) | (f2bf_bits(hi) << 16); }
__device__ __forceinline__ u32 cvtpk(float lo, float hi){ u32 r; asm("v_cvt_pk_bf16_f32 %0, %1, %2" : "=v"(r) : "v"(lo), "v"(hi)); return r; }
__device__ __forceinline__ float sigm(float x){ return __builtin_amdgcn_rcpf(1.f + __expf(-x)); }
__device__ __forceinline__ float tanh_f(float x){ return 1.f - 2.f * __builtin_amdgcn_rcpf(1.f + __expf(2.f * x)); }
// generic DPP select: enabled dest lanes get src from (lane - shift) per CTRL; others keep old
template<int CTRL, int BANK>
__device__ __forceinline__ float pack_dpp(float oldv, float srcv){
  return __uint_as_float((u32)__builtin_amdgcn_update_dpp(
      (int)__float_as_uint(oldv), (int)__float_as_uint(srcv),
      CTRL, 0xF /*row_mask*/, BANK, false));
}

// ---------- prep kernels ----------
__global__ void k_cvt(const float* __restrict__ src, u16* __restrict__ dst, int n){
  int i = (blockIdx.x * blockDim.x + threadIdx.x) * 4;
  if (i >= n) return;
  float4 v = *(const float4*)(src + i);
  uint2 o; o.x = pack2(v.x, v.y); o.y = pack2(v.z, v.w);
  *(uint2*)(dst + i) = o;
}

// Row permutation p -> orig so that wave v (of 1<<VB waves) owns rows
// [v*4U,(v+1)*4U) = {i,f,g,o} x units[v*U,(v+1)*U), U = 1<<UB units/wave.
__global__ void k_permW(const float* __restrict__ W, u16* __restrict__ Wp, int K, int UB, int VB){
  int p = blockIdx.x;
  int uo = p & ((1 << UB) - 1), g = (p >> UB) & 3, v = p >> (UB + 2);
  int orig = (g << (UB + VB)) | (v << UB) | uo;
  for (int k = threadIdx.x; k < K; k += blockDim.x)
    Wp[(size_t)p * K + k] = (u16)f2bf_bits(W[(size_t)orig * K + k]);
}

__global__ void k_permB(const float* __restrict__ b1, const float* __restrict__ b2,
                        float* __restrict__ bp, int P, int UB, int VB){
  for (int p = threadIdx.x; p < P; p += blockDim.x){
    int uo = p & ((1 << UB) - 1), g = (p >> UB) & 3, v = p >> (UB + 2);
    int orig = (g << (UB + VB)) | (v << UB) | uo;
    bp[p] = b1[orig] + b2[orig];
  }
}

// ---------- input-projection GEMM: out[m,n] = sum_k A[m,k]*W[n,k] + bias[n] ----------
// Output layout (consumed by k_rec): with n=p -> wv=p>>(UB+2), g=(p>>UB)&3,
// q=(p&mask)>>4, u=p&15, qg=q*4+g, ch=qg>>1, half=qg&1, slice=b/SB, bl=b%SB:
// u16 idx = t*TS + slice*WS + wv*VS + ch*(SB*32) + (u>>2)*(SB*8) + bl*8 + half*4 + (u&3)
template<int KTOT, bool ENC_MAP, int UB, int VB, int SB>
__global__ __launch_bounds__(256, 1) void k_xproj(const u16* __restrict__ A, const u16* __restrict__ W,
                                                  const float* __restrict__ bias, u16* __restrict__ outp){
  constexpr int NQ  = 1 << (UB - 4);
  constexpr int NCH = 2 * NQ;
  constexpr size_t VS = (size_t)NCH * SB * 32;
  constexpr size_t WS = (size_t)(1 << VB) * VS;
  constexpr size_t TS = (size_t)(B_N / SB) * WS;
  __shared__ u16 As[64][72];
  __shared__ u16 Ws[64][72];
  const int tid = threadIdx.x, l = tid & 63, v = tid >> 6;
  const int lb = l & 15, lq = l >> 4;
  const int m0 = blockIdx.x * 64, n0 = blockIdx.y * 64;
  f32x4 acc[4];
#pragma unroll
  for (int nt = 0; nt < 4; nt++){ float bv = bias[n0 + nt * 16 + lb]; f32x4 t = {bv, bv, bv, bv}; acc[nt] = t; }
  const int r = tid >> 3, c8 = (tid & 7) * 8;
  for (int kb = 0; kb < KTOT / 64; ++kb){
    __syncthreads();
    *(bf16x8*)&As[r][c8]      = *(const bf16x8*)&A[(size_t)(m0 + r) * KTOT + kb * 64 + c8];
    *(bf16x8*)&As[r + 32][c8] = *(const bf16x8*)&A[(size_t)(m0 + r + 32) * KTOT + kb * 64 + c8];
    *(bf16x8*)&Ws[r][c8]      = *(const bf16x8*)&W[(size_t)(n0 + r) * KTOT + kb * 64 + c8];
    *(bf16x8*)&Ws[r + 32][c8] = *(const bf16x8*)&W[(size_t)(n0 + r + 32) * KTOT + kb * 64 + c8];
    __syncthreads();
#pragma unroll
    for (int kc = 0; kc < 2; kc++){
      bf16x8 af = *(const bf16x8*)&As[v * 16 + lb][kc * 32 + lq * 8];
#pragma unroll
      for (int nt = 0; nt < 4; nt++){
        bf16x8 wf = *(const bf16x8*)&Ws[nt * 16 + lb][kc * 32 + lq * 8];
        acc[nt] = __builtin_amdgcn_mfma_f32_16x16x32_bf16(af, wf, acc[nt], 0, 0, 0);
      }
    }
  }
#pragma unroll
  for (int nt = 0; nt < 4; nt++){
    const int n  = n0 + nt * 16 + lb;
    const int wv = n >> (UB + 2);
    const int g  = (n >> UB) & 3;
    const int w  = n & ((1 << UB) - 1);
    const int q  = w >> 4;
    const int u  = w & 15;
    const int qg = q * 4 + g;
    const size_t nbase = (size_t)wv * VS + (size_t)(qg >> 1) * (SB * 32) + (size_t)(u >> 2) * (SB * 8)
                       + (size_t)(qg & 1) * 4 + (size_t)(u & 3);
#pragma unroll
    for (int j = 0; j < 4; j += 2){
      const u32 pk = cvtpk(acc[nt][j], acc[nt][j + 1]);
#pragma unroll
      for (int s = 0; s < 2; ++s){
        const int m = m0 + v * 16 + lq * 4 + j + s;
        const int t = ENC_MAP ? (m & 255) : (m >> 8);
        const int b = ENC_MAP ? (m >> 8)  : (m & 255);
        outp[(size_t)t * TS + (size_t)(b / SB) * WS + (size_t)(b % SB) * 8 + nbase]
            = (u16)(s ? (pk >> 16) : (pk & 0xffffu));
      }
    }
  }
}

// ---------- persistent recurrence ----------
// Grid B_N/SB wgs; wg owns batch slice of SB. Weights = A operand (M = gate rows,
// pre-permuted), h = B operand (N = batch, cols SB..15 dead). Wave v owns rows
// [v*NMT*16, (v+1)*NMT*16). Frag idx = kc*NMT+mt: [0,F_REG) regs, [F_REG,F_REG+F_LDS)
// per-wave LDS, rest volatile global (L1-hit), PREFETCHED at step start so L1 latency
// hides under the MFMA loop (R11a).
// h in B-FRAGMENT ORDER: idx(b,k) = (k>>5)*512 + ((k>>3)&3)*128 + b*8 + (k&7);
// Bh read per kc = hrd[kc*512 + l*8]: contiguous 1KB, conflict-free. ONE barrier/step.
// NQ==2 (enc): merged phases share Bh reads; DPP pack (SB=8: 1 stage; SB=4: 2 stages)
// fills all 64 lanes. NQ==1 (dec): 1-stage j-pack (R11b) -> gates 2 iters.
template<int KDIM, int NWAVE, int SB, int NMT, int NKC, int NQ, int F_REG, int F_LDS, bool IS_DEC>
__global__ __launch_bounds__(NWAVE * 64, NWAVE / 4)
void k_rec(const u16* __restrict__ Wp, const u16* __restrict__ xp,
           u16* __restrict__ enc_out, float* __restrict__ out){
  constexpr int BUFS = NKC * 512;           // u16 per h buffer (frag-order layout)
  constexpr int NCH = 2 * NQ;
  constexpr int CHS = SB * 32;              // u16 per chunk
  constexpr int F_GLB = NMT * NKC - F_REG - F_LDS;
  constexpr size_t XSTR_T = (size_t)B_N * NWAVE * NCH * 32;   // u16 per timestep (SB-invariant)
  static_assert(NMT == 4 * NQ, "tiles = 4 gates x NQ unit groups");
  static_assert(F_GLB >= 0, "reg+LDS tiers within total frags");
  extern __shared__ u16 smem[];
  u16* hbuf = smem;                          // [2][BUFS]
  u16* al   = smem + 2 * BUFS;               // [NWAVE][F_LDS][512]
  const int tid = threadIdx.x, l = tid & 63, v = tid >> 6;
  const int lb = l & 15, lq = l >> 4;
  const int b0 = blockIdx.x * SB;
  const u16* wwave = Wp + (size_t)(v * (NMT * 16) + lb) * KDIM + lq * 8;
  u16* alw = al + (size_t)v * F_LDS * 512;

  // one-time weight load: frag layout A[m=lane&15][k=quad*8+j]
  bf16x8 Areg[(F_REG > 0) ? F_REG : 1];
#pragma unroll
  for (int kc = 0; kc < NKC; ++kc)
#pragma unroll
    for (int mt = 0; mt < NMT; ++mt){
      const int idx = kc * NMT + mt;
      const u16* src = wwave + (size_t)(mt * 16) * KDIM + kc * 32;
      if (idx < F_REG)              Areg[idx] = *(const bf16x8*)src;
      else if (idx < F_REG + F_LDS) *(bf16x8*)&alw[(idx - F_REG) * 512 + l * 8] = *(const bf16x8*)src;
      // idx >= F_REG+F_LDS: stays in global (L1-resident; prefetched per step)
    }

  // xp lane base for this (slice, wave): chunk i at +i*CHS u16 (coalesced SB*64B/chunk)
  const u16* xpl = xp + ((size_t)blockIdx.x * NWAVE + v) * ((size_t)NCH * CHS) + lq * (SB * 8) + lb * 8;
  uint4 xq[NCH] = {};
  if (lb < SB){
#pragma unroll
    for (int i = 0; i < NCH; ++i) xq[i] = *(const uint4*)(xpl + (size_t)i * CHS);
  }

  for (int i = tid; i < 2 * BUFS; i += NWAVE * 64) hbuf[i] = 0;   // h(-1)=0 + dead b-slots
  float c[4];
#pragma unroll
  for (int j = 0; j < 4; j++) c[j] = 0.f;
  __syncthreads();

  for (int t = 0; t < T_N; ++t){
    const u16* hrd = hbuf + (size_t)(t & 1) * BUFS;
    u16*       hwr = hbuf + (size_t)((t & 1) ^ 1) * BUFS;

    // R11a: prefetch global-tier weight frags NOW; consumed ~60 MFMAs later.
    u32v4 gpre[(F_GLB > 0) ? F_GLB : 1];
    if constexpr (F_GLB > 0){
#pragma unroll
      for (int i = 0; i < F_GLB; ++i){
        const int idx = F_REG + F_LDS + i;
        const int kc = idx / NMT, mt = idx % NMT;
        gpre[i] = *(const volatile u32v4*)(wwave + (size_t)(mt * 16) * KDIM + kc * 32);
      }
    }

    if constexpr (NQ == 2){
      // ----- merged 2-phase path (enc) -----
      f32x4 acc[2][4];
#pragma unroll
      for (int ph = 0; ph < 2; ++ph)
#pragma unroll
        for (int g = 0; g < 4; ++g){
          const int qg = ph * 4 + g;
          const uint4 cx = xq[qg >> 1];
          const u32 w0 = (qg & 1) ? cx.z : cx.x;
          const u32 w1 = (qg & 1) ? cx.w : cx.y;
          acc[ph][g][0] = bflo(w0); acc[ph][g][1] = bfhi(w0);
          acc[ph][g][2] = bflo(w1); acc[ph][g][3] = bfhi(w1);
        }
      // reload ALL chunks with t+1 data (full step + barrier of lead)
      if (t + 1 < T_N && lb < SB){
#pragma unroll
        for (int ch = 0; ch < NCH; ++ch)
          xq[ch] = *(const uint4*)(xpl + XSTR_T + (size_t)ch * CHS);
      }
      __builtin_amdgcn_s_setprio(1);
#pragma unroll
      for (int kc = 0; kc < NKC; ++kc){
        const bf16x8 bh = *(const bf16x8*)&hrd[kc * 512 + l * 8];  // shared by both phases
#pragma unroll
        for (int ph = 0; ph < 2; ++ph)
#pragma unroll
          for (int g = 0; g < 4; ++g){
            const int idx = kc * NMT + g * NQ + ph;
            bf16x8 af;
            if (idx < F_REG)              af = Areg[idx];
            else if (idx < F_REG + F_LDS) af = *(const bf16x8*)&alw[(idx - F_REG) * 512 + l * 8];
            else                          af = __builtin_bit_cast(bf16x8, gpre[idx - F_REG - F_LDS]);
            acc[ph][g] = __builtin_amdgcn_mfma_f32_16x16x32_bf16(af, bh, acc[ph][g], 0, 0, 0);
          }
      }
      __builtin_amdgcn_s_setprio(0);
      if constexpr (SB == 8){
        // pack phase 1 (lanes lb<8) into lanes lb>=8; gates on 4 values/lane
        f32x4 comb[4];
#pragma unroll
        for (int g = 0; g < 4; ++g)
#pragma unroll
          for (int j = 0; j < 4; ++j)
            comb[g][j] = pack_dpp<0x118, 0xC>(acc[0][g][j], acc[1][g][j]);
        float hv[4];
#pragma unroll
        for (int j = 0; j < 4; ++j){
          float iv = sigm(comb[0][j]);
          float fv = sigm(comb[1][j]);
          float gv = tanh_f(comb[2][j]);
          float ov = sigm(comb[3][j]);
          float cc = fv * c[j] + iv * gv;
          c[j] = cc;
          hv[j] = ov * tanh_f(cc);
        }
        const int u0 = v * 32 + (lb >> 3) * 16 + lq * 4;
        const int widx = (u0 >> 5) * 512 + ((u0 >> 3) & 3) * 128 + (lb & 7) * 8 + (u0 & 7);
        uint2 hp; hp.x = cvtpk(hv[0], hv[1]); hp.y = cvtpk(hv[2], hv[3]);
        *(uint2*)&hwr[widx] = hp;
        __syncthreads();   // h(t) visible
        *(uint2*)(enc_out + (size_t)(t * 256 + b0 + (lb & 7)) * KDIM + u0) = hp;
      } else {
        // SB == 4: stage 1 pack phase1 (lanes 0..3) -> lanes 4..7
        f32x4 comb[4];
#pragma unroll
        for (int g = 0; g < 4; ++g)
#pragma unroll
          for (int j = 0; j < 4; ++j)
            comb[g][j] = pack_dpp<0x114, 0x2>(acc[0][g][j], acc[1][g][j]);
        // stage 2: pack j{2,3} (lanes 0..7) -> lanes 8..15; all 64 lanes live, 2 vals
        float fin[4][2];
#pragma unroll
        for (int g = 0; g < 4; ++g)
#pragma unroll
          for (int jj = 0; jj < 2; ++jj)
            fin[g][jj] = pack_dpp<0x118, 0xC>(comb[g][jj], comb[g][jj + 2]);
        float hv[2];
#pragma unroll
        for (int jj = 0; jj < 2; ++jj){
          float iv = sigm(fin[0][jj]);
          float fv = sigm(fin[1][jj]);
          float gv = tanh_f(fin[2][jj]);
          float ov = sigm(fin[3][jj]);
          float cc = fv * c[jj] + iv * gv;
          c[jj] = cc;
          hv[jj] = ov * tanh_f(cc);
        }
        // lane decode: b = lb&3, phase = (lb>>2)&1, j-half = lb>>3
        const int bq = lb & 3, ph = (lb >> 2) & 1, jh = lb >> 3;
        const int u0 = v * 32 + ph * 16 + lq * 4 + jh * 2;
        const int widx = (u0 >> 5) * 512 + ((u0 >> 3) & 3) * 128 + bq * 8 + (u0 & 7);
        const u32 hp = cvtpk(hv[0], hv[1]);
        *(u32*)&hwr[widx] = hp;
        __syncthreads();   // h(t) visible
        *(u32*)(enc_out + (size_t)(t * 256 + b0 + bq) * KDIM + u0) = hp;
      }
    } else {
      // ----- single-phase path (dec) -----
      float hv[2];
      int u0d;
      {
        const int q = 0;
        f32x4 acc[4];
#pragma unroll
        for (int g = 0; g < 4; ++g){
          const uint4 cx = xq[(q * 4 + g) >> 1];
          const u32 w0 = (g & 1) ? cx.z : cx.x;
          const u32 w1 = (g & 1) ? cx.w : cx.y;
          acc[g][0] = bflo(w0); acc[g][1] = bfhi(w0);
          acc[g][2] = bflo(w1); acc[g][3] = bfhi(w1);
        }
        if (t + 1 < T_N && lb < SB){
#pragma unroll
          for (int ch = 0; ch < NCH; ++ch)
            xq[ch] = *(const uint4*)(xpl + XSTR_T + (size_t)ch * CHS);
        }
        __builtin_amdgcn_s_setprio(1);
#pragma unroll
        for (int kc = 0; kc < NKC; ++kc){
          const bf16x8 bh = *(const bf16x8*)&hrd[kc * 512 + l * 8];
#pragma unroll
          for (int g = 0; g < 4; ++g){
            const int idx = kc * NMT + g * NQ + q;
            bf16x8 af;
            if (idx < F_REG)              af = Areg[idx];
            else if (idx < F_REG + F_LDS) af = *(const bf16x8*)&alw[(idx - F_REG) * 512 + l * 8];
            else                          af = __builtin_bit_cast(bf16x8, gpre[idx - F_REG - F_LDS]);
            acc[g] = __builtin_amdgcn_mfma_f32_16x16x32_bf16(af, bh, acc[g], 0, 0, 0);
          }
        }
        __builtin_amdgcn_s_setprio(0);
        // R11b: pack j{2,3} (lanes lb<8) into lanes lb>=8; gates 2 iters, 16 live lanes
        float fin[4][2];
#pragma unroll
        for (int g = 0; g < 4; ++g)
#pragma unroll
          for (int jj = 0; jj < 2; ++jj)
            fin[g][jj] = pack_dpp<0x118, 0xC>(acc[g][jj], acc[g][jj + 2]);
#pragma unroll
        for (int jj = 0; jj < 2; ++jj){
          float iv = sigm(fin[0][jj]);
          float fv = sigm(fin[1][jj]);
          float gv = tanh_f(fin[2][jj]);
          float ov = sigm(fin[3][jj]);
          float cc = fv * c[jj] + iv * gv;
          c[jj] = cc;
          hv[jj] = ov * tanh_f(cc);
        }
        // lane decode: b = lb&7, j-half = lb>>3
        u0d = v * 16 + lq * 4 + (lb >> 3) * 2;
        const int widx = (u0d >> 5) * 512 + ((u0d >> 3) & 3) * 128 + (lb & 7) * 8 + (u0d & 7);
        const u32 hp = cvtpk(hv[0], hv[1]);
        *(u32*)&hwr[widx] = hp;
      }
      __syncthreads();
      {
        float2 o2; o2.x = hv[0]; o2.y = hv[1];
        *(float2*)(out + ((size_t)(b0 + (lb & 7)) * T_N + t) * D_N + u0d) = o2;
      }
    }
    xpl += XSTR_T;
  }
}

extern "C" void kernel_launch(void* const* d_in, const int* in_sizes, int n_in,
                              void* d_out, int out_size, void* d_ws, size_t ws_size,
                              hipStream_t stream){
  const float* x    = (const float*)d_in[0];
  const float* eWih = (const float*)d_in[1];
  const float* eWhh = (const float*)d_in[2];
  const float* ebih = (const float*)d_in[3];
  const float* ebhh = (const float*)d_in[4];
  const float* dWih = (const float*)d_in[5];
  const float* dWhh = (const float*)d_in[6];
  const float* dbih = (const float*)d_in[7];
  const float* dbhh = (const float*)d_in[8];
  float* out = (float*)d_out;

  char* w = (char*)d_ws;
  size_t off = 0;
  auto carve = [&](size_t bytes) -> void* { void* p = w + off; off = (off + bytes + 255) & ~(size_t)255; return p; };
  u16*   xb    = (u16*)carve((size_t)B_N * T_N * D_N * 2);          // x in bf16
  u16*   WihEp = (u16*)carve((size_t)4 * H_N * D_N * 2);            // permuted enc Wih (UB=5,VB=3)
  u16*   WhhEp = (u16*)carve((size_t)4 * H_N * H_N * 2);            // permuted enc Whh (UB=5,VB=3)
  u16*   WihDp = (u16*)carve((size_t)4 * D_N * H_N * 2);            // permuted dec Wih (UB=4,VB=3)
  u16*   WhhDp = (u16*)carve((size_t)4 * D_N * D_N * 2);            // permuted dec Whh (UB=4,VB=3)
  float* bE    = (float*)carve((size_t)4 * H_N * 4);
  float* bD    = (float*)carve((size_t)4 * D_N * 4);
  u16*   xpE   = (u16*)carve((size_t)T_N * B_N * 4 * H_N * 2);      // swizzled [t][slice][v][ch][lq][bl][8]
  u16*   enc   = (u16*)carve((size_t)T_N * B_N * H_N * 2);          // encoded [T][B][H] bf16
  u16*   xpD   = (u16*)carve((size_t)T_N * B_N * 4 * D_N * 2);      // swizzled, dec
  (void)ws_size; (void)in_sizes; (void)n_in; (void)out_size;

  hipLaunchKernelGGL(k_cvt, dim3((B_N * T_N * D_N) / 1024), dim3(256), 0, stream, x, xb, B_N * T_N * D_N);
  hipLaunchKernelGGL(k_permW, dim3(1024), dim3(128), 0, stream, eWih, WihEp, 128, 5, 3);
  hipLaunchKernelGGL(k_permW, dim3(1024), dim3(128), 0, stream, eWhh, WhhEp, 256, 5, 3);
  hipLaunchKernelGGL(k_permW, dim3(512),  dim3(128), 0, stream, dWih, WihDp, 256, 4, 3);
  hipLaunchKernelGGL(k_permW, dim3(512),  dim3(128), 0, stream, dWhh, WhhDp, 128, 4, 3);
  hipLaunchKernelGGL(k_permB, dim3(1), dim3(256), 0, stream, ebih, ebhh, bE, 1024, 5, 3);
  hipLaunchKernelGGL(k_permB, dim3(1), dim3(256), 0, stream, dbih, dbhh, bD, 512, 4, 3);

  // enc x-proj: [65536,1024] = xb @ WihEp^T  (A rows m=b*T+t); SB=4 layout
  hipLaunchKernelGGL((k_xproj<128, true, 5, 3, 4>),  dim3(1024, 16), dim3(256), 0, stream, xb,  WihEp, bE, xpE);
  // enc recurrence: SB=4, 64 wgs, 8 waves (2/SIMD), 44 reg + 18 LDS + 2 global frags
  // LDS: 2*8*512*2 + 8*18*1024 = 163840 B (exactly 160 KiB)
  hipLaunchKernelGGL((k_rec<256, 8, 4, 8, 8, 2, 44, 18, false>), dim3(64), dim3(512),
                     2 * 8 * 512 * 2 + 8 * 18 * 1024, stream, WhhEp, xpE, enc, (float*)nullptr);
  // dec x-proj: [65536,512] = enc @ WihDp^T (A rows m=t*B+b); SB=8 layout
  hipLaunchKernelGGL((k_xproj<256, false, 4, 3, 8>), dim3(1024, 8),  dim3(256), 0, stream, enc, WihDp, bD, xpD);
  // dec recurrence: SB=8, 32 wgs, 8 waves (2/SIMD), all 16 frags in regs; fp32 out
  // LDS: 2*4*512*2 = 8192 B
  hipLaunchKernelGGL((k_rec<128, 8, 8, 4, 4, 1, 16, 0, true>),  dim3(32), dim3(512),
                     2 * 4 * 512 * 2, stream, WhhDp, xpD, (u16*)nullptr, out);
}

// Round 11
// 982.342 us; speedup vs baseline: 1.2869x; 1.0279x over previous
//
#include <hip/hip_runtime.h>
#include <stdint.h>

// LSTM autoencoder: B=256,T=256,D=128,H=256, gate order i,f,g,o.
// R1: persistent recurrence, full on-chip weight residency, double-buffered h.
// R3: pre-swizzled xp (coalesced dwordx4 reload in place), cvt_pk.
// R4/R5: enc recurrence 2 waves/SIMD (8 waves, NMT=8, NQ=2); reg+LDS+global frag tiers;
//     streamed Bh; xp chunk reload in place.
// R6: conflict-free frag-order h layout; acc init from xp; setprio around MFMA.
// R7/R8: enc phase-merge + DPP lane-packing (row_shr:8), gates once on 64 live lanes.
// R10: enc SB=4 (64 wgs), double DPP pack -> gates 2 iters. 533us enc, 1051 total.
// R11: (a) global-tier prefetch REGRESSED (reverted); (b) dec j-pack WON (kept). 1010.
// R12 (FAILED NaN): k_xproj __launch_bounds__(256,4) forced a 128-VGPR cap -> spill
//     -> NaN. k_rec itself was all-proven code. REVERTED to (256,1).
// R13: (a) xproj launch_bounds back to (256,1). (b) 7 prep launches fused into one
//     k_prep (blockIdx-range dispatch; outputs disjoint, no barriers) -> saves ~6
//     inter-dispatch gaps.

#define B_N 256
#define T_N 256
#define D_N 128
#define H_N 256

typedef __attribute__((ext_vector_type(8))) short bf16x8;  // MFMA A/B frag (4 VGPRs)
typedef __attribute__((ext_vector_type(4))) float f32x4;   // MFMA C/D frag
typedef unsigned short u16;
typedef unsigned int u32;
typedef __attribute__((ext_vector_type(4))) u32 u32v4;     // builtin vec: volatile-loadable

__device__ __forceinline__ float bflo(u32 u){ return __uint_as_float(u << 16); }
__device__ __forceinline__ float bfhi(u32 u){ return __uint_as_float(u & 0xffff0000u); }
__device__ __forceinline__ u32 f2bf_bits(float f){ u32 u = __float_as_uint(f); return (u + 0x7fffu + ((u >> 16) & 1u)) >> 16; }
__device__ __forceinline__ u32 pack2(float lo, float hi){ return f2bf_bits(lo) | (f2bf_bits(hi) << 16); }
__device__ __forceinline__ u32 cvtpk(float lo, float hi){ u32 r; asm("v_cvt_pk_bf16_f32 %0, %1, %2" : "=v"(r) : "v"(lo), "v"(hi)); return r; }
__device__ __forceinline__ float sigm(float x){ return __builtin_amdgcn_rcpf(1.f + __expf(-x)); }
__device__ __forceinline__ float tanh_f(float x){ return 1.f - 2.f * __builtin_amdgcn_rcpf(1.f + __expf(2.f * x)); }
// generic DPP select: enabled dest lanes get src from (lane - shift) per CTRL; others keep old
template<int CTRL, int BANK>
__device__ __forceinline__ float pack_dpp(float oldv, float srcv){
  return __uint_as_float((u32)__builtin_amdgcn_update_dpp(
      (int)__float_as_uint(oldv), (int)__float_as_uint(srcv),
      CTRL, 0xF /*row_mask*/, BANK, false));
}

// ---------- fused prep kernel (R13) ----------
// blocks [0,8192): x fp32 -> xb bf16 (4 elems/thread)
// blocks [8192,9216): permW enc Wih (K=128, UB=5, VB=3)
// blocks [9216,10240): permW enc Whh (K=256, UB=5, VB=3)
// blocks [10240,10752): permW dec Wih (K=256, UB=4, VB=3)
// blocks [10752,11264): permW dec Whh (K=128, UB=4, VB=3)
// blocks 11264, 11265: permB enc / dec
// perm: p = (v<<(UB+2))|(g<<UB)|uo  ->  orig = (g<<(UB+VB))|(v<<UB)|uo
__global__ __launch_bounds__(256) void k_prep(
    const float* __restrict__ x, u16* __restrict__ xb,
    const float* __restrict__ eWih, u16* __restrict__ WihEp,
    const float* __restrict__ eWhh, u16* __restrict__ WhhEp,
    const float* __restrict__ dWih, u16* __restrict__ WihDp,
    const float* __restrict__ dWhh, u16* __restrict__ WhhDp,
    const float* __restrict__ ebih, const float* __restrict__ ebhh, float* __restrict__ bE,
    const float* __restrict__ dbih, const float* __restrict__ dbhh, float* __restrict__ bD){
  int blk = blockIdx.x;
  if (blk < 8192){
    const int i = (blk * 256 + threadIdx.x) * 4;
    float4 v = *(const float4*)(x + i);
    uint2 o; o.x = pack2(v.x, v.y); o.y = pack2(v.z, v.w);
    *(uint2*)(xb + i) = o;
    return;
  }
  blk -= 8192;
  const float* W; u16* Wp; int K, UB, VB = 3;
  if (blk < 1024){                 W = eWih; Wp = WihEp; K = 128; UB = 5; }
  else if (blk < 2048){ blk -= 1024; W = eWhh; Wp = WhhEp; K = 256; UB = 5; }
  else if (blk < 2560){ blk -= 2048; W = dWih; Wp = WihDp; K = 256; UB = 4; }
  else if (blk < 3072){ blk -= 2560; W = dWhh; Wp = WhhDp; K = 128; UB = 4; }
  else {
    blk -= 3072;                   // 0 = enc biases, 1 = dec biases
    const float* b1 = blk ? dbih : ebih;
    const float* b2 = blk ? dbhh : ebhh;
    float* bp = blk ? bD : bE;
    const int P = blk ? 512 : 1024, UBb = blk ? 4 : 5;
    for (int p = threadIdx.x; p < P; p += 256){
      int uo = p & ((1 << UBb) - 1), g = (p >> UBb) & 3, v = p >> (UBb + 2);
      int orig = (g << (UBb + 3)) | (v << UBb) | uo;
      bp[p] = b1[orig] + b2[orig];
    }
    return;
  }
  const int p = blk;
  const int uo = p & ((1 << UB) - 1), g = (p >> UB) & 3, v = p >> (UB + 2);
  const int orig = (g << (UB + VB)) | (v << UB) | uo;
  for (int k = threadIdx.x; k < K; k += 256)
    Wp[(size_t)p * K + k] = (u16)f2bf_bits(W[(size_t)orig * K + k]);
}

// ---------- input-projection GEMM: out[m,n] = sum_k A[m,k]*W[n,k] + bias[n] ----------
// Output layout (consumed by k_rec): with n=p -> wv=p>>(UB+2), g=(p>>UB)&3,
// q=(p&mask)>>4, u=p&15, qg=q*4+g, ch=qg>>1, half=qg&1, slice=b/SB, bl=b%SB:
// u16 idx = t*TS + slice*WS + wv*VS + ch*(SB*32) + (u>>2)*(SB*8) + bl*8 + half*4 + (u&3)
template<int KTOT, bool ENC_MAP, int UB, int VB, int SB>
__global__ __launch_bounds__(256, 1) void k_xproj(const u16* __restrict__ A, const u16* __restrict__ W,
                                                  const float* __restrict__ bias, u16* __restrict__ outp){
  constexpr int NQ  = 1 << (UB - 4);
  constexpr int NCH = 2 * NQ;
  constexpr size_t VS = (size_t)NCH * SB * 32;
  constexpr size_t WS = (size_t)(1 << VB) * VS;
  constexpr size_t TS = (size_t)(B_N / SB) * WS;
  __shared__ u16 As[64][72];
  __shared__ u16 Ws[64][72];
  const int tid = threadIdx.x, l = tid & 63, v = tid >> 6;
  const int lb = l & 15, lq = l >> 4;
  const int m0 = blockIdx.x * 64, n0 = blockIdx.y * 64;
  f32x4 acc[4];
#pragma unroll
  for (int nt = 0; nt < 4; nt++){ float bv = bias[n0 + nt * 16 + lb]; f32x4 t = {bv, bv, bv, bv}; acc[nt] = t; }
  const int r = tid >> 3, c8 = (tid & 7) * 8;
  for (int kb = 0; kb < KTOT / 64; ++kb){
    __syncthreads();
    *(bf16x8*)&As[r][c8]      = *(const bf16x8*)&A[(size_t)(m0 + r) * KTOT + kb * 64 + c8];
    *(bf16x8*)&As[r + 32][c8] = *(const bf16x8*)&A[(size_t)(m0 + r + 32) * KTOT + kb * 64 + c8];
    *(bf16x8*)&Ws[r][c8]      = *(const bf16x8*)&W[(size_t)(n0 + r) * KTOT + kb * 64 + c8];
    *(bf16x8*)&Ws[r + 32][c8] = *(const bf16x8*)&W[(size_t)(n0 + r + 32) * KTOT + kb * 64 + c8];
    __syncthreads();
#pragma unroll
    for (int kc = 0; kc < 2; kc++){
      bf16x8 af = *(const bf16x8*)&As[v * 16 + lb][kc * 32 + lq * 8];
#pragma unroll
      for (int nt = 0; nt < 4; nt++){
        bf16x8 wf = *(const bf16x8*)&Ws[nt * 16 + lb][kc * 32 + lq * 8];
        acc[nt] = __builtin_amdgcn_mfma_f32_16x16x32_bf16(af, wf, acc[nt], 0, 0, 0);
      }
    }
  }
#pragma unroll
  for (int nt = 0; nt < 4; nt++){
    const int n  = n0 + nt * 16 + lb;
    const int wv = n >> (UB + 2);
    const int g  = (n >> UB) & 3;
    const int w  = n & ((1 << UB) - 1);
    const int q  = w >> 4;
    const int u  = w & 15;
    const int qg = q * 4 + g;
    const size_t nbase = (size_t)wv * VS + (size_t)(qg >> 1) * (SB * 32) + (size_t)(u >> 2) * (SB * 8)
                       + (size_t)(qg & 1) * 4 + (size_t)(u & 3);
#pragma unroll
    for (int j = 0; j < 4; j += 2){
      const u32 pk = cvtpk(acc[nt][j], acc[nt][j + 1]);
#pragma unroll
      for (int s = 0; s < 2; ++s){
        const int m = m0 + v * 16 + lq * 4 + j + s;
        const int t = ENC_MAP ? (m & 255) : (m >> 8);
        const int b = ENC_MAP ? (m >> 8)  : (m & 255);
        outp[(size_t)t * TS + (size_t)(b / SB) * WS + (size_t)(b % SB) * 8 + nbase]
            = (u16)(s ? (pk >> 16) : (pk & 0xffffu));
      }
    }
  }
}

// ---------- persistent recurrence ----------
// Grid B_N/SB wgs; wg owns batch slice of SB. Weights = A operand (M = gate rows,
// pre-permuted), h = B operand (N = batch, cols SB..15 dead). Wave v owns rows
// [v*NMT*16, (v+1)*NMT*16). Frag idx = kc*NMT+mt: [0,F_REG) regs, [F_REG,F_REG+F_LDS)
// per-wave LDS, rest INLINE volatile global (L1-hit; R11 prefetch regressed).
// h in B-FRAGMENT ORDER: idx(b,k) = (k>>5)*512 + ((k>>3)&3)*128 + b*8 + (k&7);
// Bh read per kc = hrd[kc*512 + l*8]: contiguous 1KB, conflict-free. ONE barrier/step.
// NQ==2 (enc): merged phases share Bh reads; DPP pack (SB=8: 1 stage; SB=4: 2 stages)
// fills all 64 lanes. NQ==1 (dec): 1-stage j-pack -> gates 2 iters.
template<int KDIM, int NWAVE, int SB, int NMT, int NKC, int NQ, int F_REG, int F_LDS, bool IS_DEC>
__global__ __launch_bounds__(NWAVE * 64, NWAVE / 4)
void k_rec(const u16* __restrict__ Wp, const u16* __restrict__ xp,
           u16* __restrict__ enc_out, float* __restrict__ out){
  constexpr int BUFS = NKC * 512;           // u16 per h buffer (frag-order layout)
  constexpr int NCH = 2 * NQ;
  constexpr int CHS = SB * 32;              // u16 per chunk
  constexpr size_t XSTR_T = (size_t)B_N * NWAVE * NCH * 32;   // u16 per timestep (SB-invariant)
  static_assert(NMT == 4 * NQ, "tiles = 4 gates x NQ unit groups");
  static_assert(F_REG + F_LDS <= NMT * NKC, "reg+LDS tiers within total frags");
  extern __shared__ u16 smem[];
  u16* hbuf = smem;                          // [2][BUFS]
  u16* al   = smem + 2 * BUFS;               // [NWAVE][F_LDS][512]
  const int tid = threadIdx.x, l = tid & 63, v = tid >> 6;
  const int lb = l & 15, lq = l >> 4;
  const int b0 = blockIdx.x * SB;
  const u16* wwave = Wp + (size_t)(v * (NMT * 16) + lb) * KDIM + lq * 8;
  u16* alw = al + (size_t)v * F_LDS * 512;

  // one-time weight load: frag layout A[m=lane&15][k=quad*8+j]
  bf16x8 Areg[(F_REG > 0) ? F_REG : 1];
#pragma unroll
  for (int kc = 0; kc < NKC; ++kc)
#pragma unroll
    for (int mt = 0; mt < NMT; ++mt){
      const int idx = kc * NMT + mt;
      const u16* src = wwave + (size_t)(mt * 16) * KDIM + kc * 32;
      if (idx < F_REG)              Areg[idx] = *(const bf16x8*)src;
      else if (idx < F_REG + F_LDS) *(bf16x8*)&alw[(idx - F_REG) * 512 + l * 8] = *(const bf16x8*)src;
      // idx >= F_REG+F_LDS: stays in global (L1-resident; inline volatile read per use)
    }

  // xp lane base for this (slice, wave): chunk i at +i*CHS u16 (coalesced SB*64B/chunk)
  const u16* xpl = xp + ((size_t)blockIdx.x * NWAVE + v) * ((size_t)NCH * CHS) + lq * (SB * 8) + lb * 8;
  uint4 xq[NCH] = {};
  if (lb < SB){
#pragma unroll
    for (int i = 0; i < NCH; ++i) xq[i] = *(const uint4*)(xpl + (size_t)i * CHS);
  }

  for (int i = tid; i < 2 * BUFS; i += NWAVE * 64) hbuf[i] = 0;   // h(-1)=0 + dead b-slots
  float c[4];
#pragma unroll
  for (int j = 0; j < 4; j++) c[j] = 0.f;
  __syncthreads();

  for (int t = 0; t < T_N; ++t){
    const u16* hrd = hbuf + (size_t)(t & 1) * BUFS;
    u16*       hwr = hbuf + (size_t)((t & 1) ^ 1) * BUFS;

    if constexpr (NQ == 2){
      // ----- merged 2-phase path (enc) -----
      f32x4 acc[2][4];
#pragma unroll
      for (int ph = 0; ph < 2; ++ph)
#pragma unroll
        for (int g = 0; g < 4; ++g){
          const int qg = ph * 4 + g;
          const uint4 cx = xq[qg >> 1];
          const u32 w0 = (qg & 1) ? cx.z : cx.x;
          const u32 w1 = (qg & 1) ? cx.w : cx.y;
          acc[ph][g][0] = bflo(w0); acc[ph][g][1] = bfhi(w0);
          acc[ph][g][2] = bflo(w1); acc[ph][g][3] = bfhi(w1);
        }
      // reload ALL chunks with t+1 data (full step + barrier of lead)
      if (t + 1 < T_N && lb < SB){
#pragma unroll
        for (int ch = 0; ch < NCH; ++ch)
          xq[ch] = *(const uint4*)(xpl + XSTR_T + (size_t)ch * CHS);
      }
      __builtin_amdgcn_s_setprio(1);
#pragma unroll
      for (int kc = 0; kc < NKC; ++kc){
        const bf16x8 bh = *(const bf16x8*)&hrd[kc * 512 + l * 8];  // shared by both phases
#pragma unroll
        for (int ph = 0; ph < 2; ++ph)
#pragma unroll
          for (int g = 0; g < 4; ++g){
            const int idx = kc * NMT + g * NQ + ph;
            bf16x8 af;
            if (idx < F_REG)              af = Areg[idx];
            else if (idx < F_REG + F_LDS) af = *(const bf16x8*)&alw[(idx - F_REG) * 512 + l * 8];
            else {                         // L1-resident global tier; volatile defeats LICM
              const int mt = g * NQ + ph;
              u32v4 gw = *(const volatile u32v4*)(wwave + (size_t)(mt * 16) * KDIM + kc * 32);
              af = __builtin_bit_cast(bf16x8, gw);
            }
            acc[ph][g] = __builtin_amdgcn_mfma_f32_16x16x32_bf16(af, bh, acc[ph][g], 0, 0, 0);
          }
      }
      __builtin_amdgcn_s_setprio(0);
      if constexpr (SB == 8){
        // pack phase 1 (lanes lb<8) into lanes lb>=8; gates on 4 values/lane
        f32x4 comb[4];
#pragma unroll
        for (int g = 0; g < 4; ++g)
#pragma unroll
          for (int j = 0; j < 4; ++j)
            comb[g][j] = pack_dpp<0x118, 0xC>(acc[0][g][j], acc[1][g][j]);
        float hv[4];
#pragma unroll
        for (int j = 0; j < 4; ++j){
          float iv = sigm(comb[0][j]);
          float fv = sigm(comb[1][j]);
          float gv = tanh_f(comb[2][j]);
          float ov = sigm(comb[3][j]);
          float cc = fv * c[j] + iv * gv;
          c[j] = cc;
          hv[j] = ov * tanh_f(cc);
        }
        const int u0 = v * 32 + (lb >> 3) * 16 + lq * 4;
        const int widx = (u0 >> 5) * 512 + ((u0 >> 3) & 3) * 128 + (lb & 7) * 8 + (u0 & 7);
        uint2 hp; hp.x = cvtpk(hv[0], hv[1]); hp.y = cvtpk(hv[2], hv[3]);
        *(uint2*)&hwr[widx] = hp;
        __syncthreads();   // h(t) visible
        *(uint2*)(enc_out + (size_t)(t * 256 + b0 + (lb & 7)) * KDIM + u0) = hp;
      } else {
        // SB == 4: stage 1 pack phase1 (lanes 0..3) -> lanes 4..7
        f32x4 comb[4];
#pragma unroll
        for (int g = 0; g < 4; ++g)
#pragma unroll
          for (int j = 0; j < 4; ++j)
            comb[g][j] = pack_dpp<0x114, 0x2>(acc[0][g][j], acc[1][g][j]);
        // stage 2: pack j{2,3} (lanes 0..7) -> lanes 8..15; all 64 lanes live, 2 vals
        float fin[4][2];
#pragma unroll
        for (int g = 0; g < 4; ++g)
#pragma unroll
          for (int jj = 0; jj < 2; ++jj)
            fin[g][jj] = pack_dpp<0x118, 0xC>(comb[g][jj], comb[g][jj + 2]);
        float hv[2];
#pragma unroll
        for (int jj = 0; jj < 2; ++jj){
          float iv = sigm(fin[0][jj]);
          float fv = sigm(fin[1][jj]);
          float gv = tanh_f(fin[2][jj]);
          float ov = sigm(fin[3][jj]);
          float cc = fv * c[jj] + iv * gv;
          c[jj] = cc;
          hv[jj] = ov * tanh_f(cc);
        }
        // lane decode: b = lb&3, phase = (lb>>2)&1, j-half = lb>>3
        const int bq = lb & 3, ph = (lb >> 2) & 1, jh = lb >> 3;
        const int u0 = v * 32 + ph * 16 + lq * 4 + jh * 2;
        const int widx = (u0 >> 5) * 512 + ((u0 >> 3) & 3) * 128 + bq * 8 + (u0 & 7);
        const u32 hp = cvtpk(hv[0], hv[1]);
        *(u32*)&hwr[widx] = hp;
        __syncthreads();   // h(t) visible
        *(u32*)(enc_out + (size_t)(t * 256 + b0 + bq) * KDIM + u0) = hp;
      }
    } else {
      // ----- single-phase path (dec) -----
      float hv[2];
      int u0d;
      {
        const int q = 0;
        f32x4 acc[4];
#pragma unroll
        for (int g = 0; g < 4; ++g){
          const uint4 cx = xq[(q * 4 + g) >> 1];
          const u32 w0 = (g & 1) ? cx.z : cx.x;
          const u32 w1 = (g & 1) ? cx.w : cx.y;
          acc[g][0] = bflo(w0); acc[g][1] = bfhi(w0);
          acc[g][2] = bflo(w1); acc[g][3] = bfhi(w1);
        }
        if (t + 1 < T_N && lb < SB){
#pragma unroll
          for (int ch = 0; ch < NCH; ++ch)
            xq[ch] = *(const uint4*)(xpl + XSTR_T + (size_t)ch * CHS);
        }
        __builtin_amdgcn_s_setprio(1);
#pragma unroll
        for (int kc = 0; kc < NKC; ++kc){
          const bf16x8 bh = *(const bf16x8*)&hrd[kc * 512 + l * 8];
#pragma unroll
          for (int g = 0; g < 4; ++g){
            const int idx = kc * NMT + g * NQ + q;
            bf16x8 af;
            if (idx < F_REG)              af = Areg[idx];
            else if (idx < F_REG + F_LDS) af = *(const bf16x8*)&alw[(idx - F_REG) * 512 + l * 8];
            else {
              const int mt = g * NQ + q;
              u32v4 gw = *(const volatile u32v4*)(wwave + (size_t)(mt * 16) * KDIM + kc * 32);
              af = __builtin_bit_cast(bf16x8, gw);
            }
            acc[g] = __builtin_amdgcn_mfma_f32_16x16x32_bf16(af, bh, acc[g], 0, 0, 0);
          }
        }
        __builtin_amdgcn_s_setprio(0);
        // pack j{2,3} (lanes lb<8) into lanes lb>=8; gates 2 iters, all lanes live
        float fin[4][2];
#pragma unroll
        for (int g = 0; g < 4; ++g)
#pragma unroll
          for (int jj = 0; jj < 2; ++jj)
            fin[g][jj] = pack_dpp<0x118, 0xC>(acc[g][jj], acc[g][jj + 2]);
#pragma unroll
        for (int jj = 0; jj < 2; ++jj){
          float iv = sigm(fin[0][jj]);
          float fv = sigm(fin[1][jj]);
          float gv = tanh_f(fin[2][jj]);
          float ov = sigm(fin[3][jj]);
          float cc = fv * c[jj] + iv * gv;
          c[jj] = cc;
          hv[jj] = ov * tanh_f(cc);
        }
        // lane decode: b = lb&7, j-half = lb>>3
        u0d = v * 16 + lq * 4 + (lb >> 3) * 2;
        const int widx = (u0d >> 5) * 512 + ((u0d >> 3) & 3) * 128 + (lb & 7) * 8 + (u0d & 7);
        const u32 hp = cvtpk(hv[0], hv[1]);
        *(u32*)&hwr[widx] = hp;
      }
      __syncthreads();
      {
        float2 o2; o2.x = hv[0]; o2.y = hv[1];
        *(float2*)(out + ((size_t)(b0 + (lb & 7)) * T_N + t) * D_N + u0d) = o2;
      }
    }
    xpl += XSTR_T;
  }
}

extern "C" void kernel_launch(void* const* d_in, const int* in_sizes, int n_in,
                              void* d_out, int out_size, void* d_ws, size_t ws_size,
                              hipStream_t stream){
  const float* x    = (const float*)d_in[0];
  const float* eWih = (const float*)d_in[1];
  const float* eWhh = (const float*)d_in[2];
  const float* ebih = (const float*)d_in[3];
  const float* ebhh = (const float*)d_in[4];
  const float* dWih = (const float*)d_in[5];
  const float* dWhh = (const float*)d_in[6];
  const float* dbih = (const float*)d_in[7];
  const float* dbhh = (const float*)d_in[8];
  float* out = (float*)d_out;

  char* w = (char*)d_ws;
  size_t off = 0;
  auto carve = [&](size_t bytes) -> void* { void* p = w + off; off = (off + bytes + 255) & ~(size_t)255; return p; };
  u16*   xb    = (u16*)carve((size_t)B_N * T_N * D_N * 2);          // x in bf16
  u16*   WihEp = (u16*)carve((size_t)4 * H_N * D_N * 2);            // permuted enc Wih (UB=5,VB=3)
  u16*   WhhEp = (u16*)carve((size_t)4 * H_N * H_N * 2);            // permuted enc Whh (UB=5,VB=3)
  u16*   WihDp = (u16*)carve((size_t)4 * D_N * H_N * 2);            // permuted dec Wih (UB=4,VB=3)
  u16*   WhhDp = (u16*)carve((size_t)4 * D_N * D_N * 2);            // permuted dec Whh (UB=4,VB=3)
  float* bE    = (float*)carve((size_t)4 * H_N * 4);
  float* bD    = (float*)carve((size_t)4 * D_N * 4);
  u16*   xpE   = (u16*)carve((size_t)T_N * B_N * 4 * H_N * 2);      // swizzled [t][slice][v][ch][lq][bl][8]
  u16*   enc   = (u16*)carve((size_t)T_N * B_N * H_N * 2);          // encoded [T][B][H] bf16
  u16*   xpD   = (u16*)carve((size_t)T_N * B_N * 4 * D_N * 2);      // swizzled, dec
  (void)ws_size; (void)in_sizes; (void)n_in; (void)out_size;

  // fused prep: cvt (8192 blocks) + 4x permW (3072) + 2x permB
  hipLaunchKernelGGL(k_prep, dim3(8192 + 3072 + 2), dim3(256), 0, stream,
                     x, xb, eWih, WihEp, eWhh, WhhEp, dWih, WihDp, dWhh, WhhDp,
                     ebih, ebhh, bE, dbih, dbhh, bD);

  // enc x-proj: [65536,1024] = xb @ WihEp^T  (A rows m=b*T+t); SB=4 layout
  hipLaunchKernelGGL((k_xproj<128, true, 5, 3, 4>),  dim3(1024, 16), dim3(256), 0, stream, xb,  WihEp, bE, xpE);
  // enc recurrence: SB=4, 64 wgs, 8 waves (2/SIMD), 44 reg + 18 LDS + 2 global frags
  // LDS: 2*8*512*2 + 8*18*1024 = 163840 B (exactly 160 KiB)
  hipLaunchKernelGGL((k_rec<256, 8, 4, 8, 8, 2, 44, 18, false>), dim3(64), dim3(512),
                     2 * 8 * 512 * 2 + 8 * 18 * 1024, stream, WhhEp, xpE, enc, (float*)nullptr);
  // dec x-proj: [65536,512] = enc @ WihDp^T (A rows m=t*B+b); SB=8 layout
  hipLaunchKernelGGL((k_xproj<256, false, 4, 3, 8>), dim3(1024, 8),  dim3(256), 0, stream, enc, WihDp, bD, xpD);
  // dec recurrence: SB=8, 32 wgs, 8 waves (2/SIMD), all 16 frags in regs; fp32 out
  // LDS: 2*4*512*2 = 8192 B
  hipLaunchKernelGGL((k_rec<128, 8, 8, 4, 4, 1, 16, 0, true>),  dim3(32), dim3(512),
                     2 * 4 * 512 * 2, stream, WhhDp, xpD, (u16*)nullptr, out);
}

// Round 12
// 912.057 us; speedup vs baseline: 1.3861x; 1.0771x over previous
//
#include <hip/hip_runtime.h>
#include <stdint.h>

// LSTM autoencoder: B=256,T=256,D=128,H=256, gate order i,f,g,o.
// R1: persistent recurrence, full on-chip weight residency, double-buffered h.
// R3: pre-swizzled xp (coalesced dwordx4 reload in place), cvt_pk.
// R4/R5: enc recurrence 2 waves/SIMD (8 waves, NMT=8, NQ=2); reg+LDS+global frag tiers.
// R6: conflict-free frag-order h layout; acc init from xp; setprio around MFMA.
// R7/R8: enc phase-merge + DPP lane-packing; gates on all 64 lanes.
// R10: enc SB=4 (64 wgs), double DPP pack -> gates 2 iters. 533us enc.
// R11: dec j-pack (row_shr:8/bankC) -> gates 2 iters (kept); prefetch reverted.
// R13: fused prep; xproj launch_bounds (256,1). 982 total, enc rec 532.
// R14: xproj epilogue rewrite. Old: 16x 2-byte scattered global stores/thread (8B runs
//     64B apart -> HBM sector write amplification; xprojs ~245us for 34 GFLOP).
//     New: (a) x transposed to [T][B][D] in prep so BOTH xprojs use m = t*B+b (m-tile
//     = one t-plane); (b) 64x64 output tile staged in 8KB LDS in swizzled form (XOR
//     ((loff>>6)&7)<<3 on write AND flush-read -> bank-conflict-free, cancels), then
//     flushed with coalesced dwordx4: dec = 8x 1KB contiguous blocks, enc = 16 slices
//     x 2x 256B ch-blocks. k_rec (both) untouched.

#define B_N 256
#define T_N 256
#define D_N 128
#define H_N 256

typedef __attribute__((ext_vector_type(8))) short bf16x8;  // MFMA A/B frag (4 VGPRs)
typedef __attribute__((ext_vector_type(4))) float f32x4;   // MFMA C/D frag
typedef unsigned short u16;
typedef unsigned int u32;
typedef __attribute__((ext_vector_type(4))) u32 u32v4;     // builtin vec: volatile-loadable

__device__ __forceinline__ float bflo(u32 u){ return __uint_as_float(u << 16); }
__device__ __forceinline__ float bfhi(u32 u){ return __uint_as_float(u & 0xffff0000u); }
__device__ __forceinline__ u32 f2bf_bits(float f){ u32 u = __float_as_uint(f); return (u + 0x7fffu + ((u >> 16) & 1u)) >> 16; }
__device__ __forceinline__ u32 pack2(float lo, float hi){ return f2bf_bits(lo) | (f2bf_bits(hi) << 16); }
__device__ __forceinline__ u32 cvtpk(float lo, float hi){ u32 r; asm("v_cvt_pk_bf16_f32 %0, %1, %2" : "=v"(r) : "v"(lo), "v"(hi)); return r; }
__device__ __forceinline__ float sigm(float x){ return __builtin_amdgcn_rcpf(1.f + __expf(-x)); }
__device__ __forceinline__ float tanh_f(float x){ return 1.f - 2.f * __builtin_amdgcn_rcpf(1.f + __expf(2.f * x)); }
// generic DPP select: enabled dest lanes get src from (lane - shift) per CTRL; others keep old
template<int CTRL, int BANK>
__device__ __forceinline__ float pack_dpp(float oldv, float srcv){
  return __uint_as_float((u32)__builtin_amdgcn_update_dpp(
      (int)__float_as_uint(oldv), (int)__float_as_uint(srcv),
      CTRL, 0xF /*row_mask*/, BANK, false));
}

// ---------- fused prep kernel ----------
// blocks [0,8192): x[B][T][D] fp32 -> xb[T][B][D] bf16 (transpose, 4 elems/thread)
// blocks [8192,9216): permW enc Wih (K=128, UB=5) ; [9216,10240): enc Whh (K=256, UB=5)
// blocks [10240,10752): dec Wih (K=256, UB=4)     ; [10752,11264): dec Whh (K=128, UB=4)
// blocks 11264,11265: permB enc/dec.  perm: p=(v<<(UB+2))|(g<<UB)|uo -> orig=(g<<(UB+3))|(v<<UB)|uo
__global__ __launch_bounds__(256) void k_prep(
    const float* __restrict__ x, u16* __restrict__ xb,
    const float* __restrict__ eWih, u16* __restrict__ WihEp,
    const float* __restrict__ eWhh, u16* __restrict__ WhhEp,
    const float* __restrict__ dWih, u16* __restrict__ WihDp,
    const float* __restrict__ dWhh, u16* __restrict__ WhhDp,
    const float* __restrict__ ebih, const float* __restrict__ ebhh, float* __restrict__ bE,
    const float* __restrict__ dbih, const float* __restrict__ dbhh, float* __restrict__ bD){
  int blk = blockIdx.x;
  if (blk < 8192){
    const int i = (blk * 256 + threadIdx.x) * 4;
    const int d = i & 127, rest = i >> 7;
    const int t = rest & 255, b = rest >> 8;
    float4 v = *(const float4*)(x + i);
    uint2 o; o.x = pack2(v.x, v.y); o.y = pack2(v.z, v.w);
    *(uint2*)(xb + (size_t)(t * 256 + b) * 128 + d) = o;
    return;
  }
  blk -= 8192;
  const float* W; u16* Wp; int K, UB;
  if (blk < 1024){                 W = eWih; Wp = WihEp; K = 128; UB = 5; }
  else if (blk < 2048){ blk -= 1024; W = eWhh; Wp = WhhEp; K = 256; UB = 5; }
  else if (blk < 2560){ blk -= 2048; W = dWih; Wp = WihDp; K = 256; UB = 4; }
  else if (blk < 3072){ blk -= 2560; W = dWhh; Wp = WhhDp; K = 128; UB = 4; }
  else {
    blk -= 3072;                   // 0 = enc biases, 1 = dec biases
    const float* b1 = blk ? dbih : ebih;
    const float* b2 = blk ? dbhh : ebhh;
    float* bp = blk ? bD : bE;
    const int P = blk ? 512 : 1024, UBb = blk ? 4 : 5;
    for (int p = threadIdx.x; p < P; p += 256){
      int uo = p & ((1 << UBb) - 1), g = (p >> UBb) & 3, v = p >> (UBb + 2);
      int orig = (g << (UBb + 3)) | (v << UBb) | uo;
      bp[p] = b1[orig] + b2[orig];
    }
    return;
  }
  const int p = blk;
  const int uo = p & ((1 << UB) - 1), g = (p >> UB) & 3, v = p >> (UB + 2);
  const int orig = (g << (UB + 3)) | (v << UB) | uo;
  for (int k = threadIdx.x; k < K; k += 256)
    Wp[(size_t)p * K + k] = (u16)f2bf_bits(W[(size_t)orig * K + k]);
}

// ---------- input-projection GEMM: out[m,n] = sum_k A[m,k]*W[n,k] + bias[n] ----------
// A rows m = t*B + b (x transposed in prep; enc intermediate already [T][B][H]).
// m-tile 64 = ONE t-plane, b-range 64. Output layout (k_rec consumer):
//   u16 idx = t*TS + (b/SB)*WS + wv*VS + (qg>>1)*(SB*32) + (u>>2)*(SB*8)
//           + (b%SB)*8 + (qg&1)*4 + (u&3),  qg = q*4+g, wv=n>>(UB+2), u=n&15.
// Epilogue stages the tile's 4096 u16 densely in LDS (XOR-swizzled), then flushes
// coalesced: dec (NQ=1) 8x512-u16 blocks; enc (NQ=2) 16 slices x 2 q-halves of 128
// (ch = q*2 + (blockIdx.y&1), since tile's g spans {g0,g0+1}, g0 even).
template<int KTOT, int UB, int VB, int SB>
__global__ __launch_bounds__(256, 1) void k_xproj(const u16* __restrict__ A, const u16* __restrict__ W,
                                                  const float* __restrict__ bias, u16* __restrict__ outp){
  constexpr int NQ  = 1 << (UB - 4);
  constexpr int NCH = 2 * NQ;
  constexpr size_t VS = (size_t)NCH * SB * 32;
  constexpr size_t WS = (size_t)(1 << VB) * VS;
  constexpr size_t TS = (size_t)(B_N / SB) * WS;
  __shared__ u16 As[64][72];
  __shared__ u16 Ws[64][72];
  __shared__ u16 ostage[4096];
  const int tid = threadIdx.x, l = tid & 63, v = tid >> 6;
  const int lb = l & 15, lq = l >> 4;
  const int m0 = blockIdx.x * 64, n0 = blockIdx.y * 64;
  f32x4 acc[4];
#pragma unroll
  for (int nt = 0; nt < 4; nt++){ float bv = bias[n0 + nt * 16 + lb]; f32x4 t = {bv, bv, bv, bv}; acc[nt] = t; }
  const int r = tid >> 3, c8 = (tid & 7) * 8;
  for (int kb = 0; kb < KTOT / 64; ++kb){
    __syncthreads();
    *(bf16x8*)&As[r][c8]      = *(const bf16x8*)&A[(size_t)(m0 + r) * KTOT + kb * 64 + c8];
    *(bf16x8*)&As[r + 32][c8] = *(const bf16x8*)&A[(size_t)(m0 + r + 32) * KTOT + kb * 64 + c8];
    *(bf16x8*)&Ws[r][c8]      = *(const bf16x8*)&W[(size_t)(n0 + r) * KTOT + kb * 64 + c8];
    *(bf16x8*)&Ws[r + 32][c8] = *(const bf16x8*)&W[(size_t)(n0 + r + 32) * KTOT + kb * 64 + c8];
    __syncthreads();
#pragma unroll
    for (int kc = 0; kc < 2; kc++){
      bf16x8 af = *(const bf16x8*)&As[v * 16 + lb][kc * 32 + lq * 8];
#pragma unroll
      for (int nt = 0; nt < 4; nt++){
        bf16x8 wf = *(const bf16x8*)&Ws[nt * 16 + lb][kc * 32 + lq * 8];
        acc[nt] = __builtin_amdgcn_mfma_f32_16x16x32_bf16(af, wf, acc[nt], 0, 0, 0);
      }
    }
  }
  // ---- stage: scatter u16 into dense LDS image (XOR-swizzled) ----
  __syncthreads();
#pragma unroll
  for (int nt = 0; nt < 4; nt++){
    const int n = n0 + nt * 16 + lb;
    const int u = lb;                        // n&15 == lb (n0, nt*16 are 16-aligned)
    int inner;
    if constexpr (NQ == 1){                  // dec: ch=g>>1, half=g&1, dense [sl][512]
      const int g = (n >> 4) & 3;
      inner = (g >> 1) * 256 + (u >> 2) * 64 + (g & 1) * 4 + (u & 3);
    } else {                                 // enc: dense [sl][q*128 + ...]
      const int q = (n >> 4) & 1, g = (n >> 5) & 3;
      inner = q * 128 + (u >> 2) * 32 + (g & 1) * 4 + (u & 3);
    }
#pragma unroll
    for (int j = 0; j < 4; j += 2){
      const u32 pk = cvtpk(acc[nt][j], acc[nt][j + 1]);
#pragma unroll
      for (int s = 0; s < 2; ++s){
        const int bl_ = v * 16 + lq * 4 + j + s;   // b within tile
        int loff;
        if constexpr (NQ == 1) loff = (bl_ >> 3) * 512 + inner + (bl_ & 7) * 8;
        else                   loff = (bl_ >> 2) * 256 + inner + (bl_ & 3) * 8;
        loff ^= ((loff >> 6) & 7) << 3;
        ostage[loff] = (u16)(s ? (pk >> 16) : (pk & 0xffffu));
      }
    }
  }
  __syncthreads();
  // ---- flush: coalesced dwordx4 ----
  {
    const int t  = m0 >> 8, b0 = m0 & 255;
    const int sl0 = (NQ == 1) ? (b0 >> 3) : (b0 >> 2);
    const int wv  = (NQ == 1) ? blockIdx.y : (blockIdx.y >> 1);
    const int cb  = blockIdx.y & 1;          // enc only: g0>>1
#pragma unroll
    for (int it = 0; it < 2; ++it){
      const int o = (it * 256 + tid) * 8;
      const int loff = o ^ (((o >> 6) & 7) << 3);
      const uint4 vdat = *(const uint4*)&ostage[loff];
      size_t dst;
      if constexpr (NQ == 1)
        dst = (size_t)t * TS + (size_t)(sl0 + (o >> 9)) * WS + (size_t)wv * VS + (o & 511);
      else {
        const int rr = o & 255, q = rr >> 7, ww = rr & 127;
        dst = (size_t)t * TS + (size_t)(sl0 + (o >> 8)) * WS + (size_t)wv * VS
            + (size_t)(q * 2 + cb) * 128 + ww;
      }
      *(uint4*)(outp + dst) = vdat;
    }
  }
}

// ---------- persistent recurrence ----------
// Grid B_N/SB wgs; wg owns batch slice of SB. Weights = A operand (M = gate rows,
// pre-permuted), h = B operand (N = batch, cols SB..15 dead). Wave v owns rows
// [v*NMT*16, (v+1)*NMT*16). Frag idx = kc*NMT+mt: [0,F_REG) regs, [F_REG,F_REG+F_LDS)
// per-wave LDS, rest INLINE volatile global (L1-hit; R11 prefetch regressed).
// h in B-FRAGMENT ORDER: idx(b,k) = (k>>5)*512 + ((k>>3)&3)*128 + b*8 + (k&7);
// Bh read per kc = hrd[kc*512 + l*8]: contiguous 1KB, conflict-free. ONE barrier/step.
// NQ==2 (enc): merged phases share Bh reads; DPP pack (SB=8: 1 stage; SB=4: 2 stages)
// fills all 64 lanes. NQ==1 (dec): 1-stage j-pack -> gates 2 iters.
template<int KDIM, int NWAVE, int SB, int NMT, int NKC, int NQ, int F_REG, int F_LDS, bool IS_DEC>
__global__ __launch_bounds__(NWAVE * 64, NWAVE / 4)
void k_rec(const u16* __restrict__ Wp, const u16* __restrict__ xp,
           u16* __restrict__ enc_out, float* __restrict__ out){
  constexpr int BUFS = NKC * 512;           // u16 per h buffer (frag-order layout)
  constexpr int NCH = 2 * NQ;
  constexpr int CHS = SB * 32;              // u16 per chunk
  constexpr size_t XSTR_T = (size_t)B_N * NWAVE * NCH * 32;   // u16 per timestep (SB-invariant)
  static_assert(NMT == 4 * NQ, "tiles = 4 gates x NQ unit groups");
  static_assert(F_REG + F_LDS <= NMT * NKC, "reg+LDS tiers within total frags");
  extern __shared__ u16 smem[];
  u16* hbuf = smem;                          // [2][BUFS]
  u16* al   = smem + 2 * BUFS;               // [NWAVE][F_LDS][512]
  const int tid = threadIdx.x, l = tid & 63, v = tid >> 6;
  const int lb = l & 15, lq = l >> 4;
  const int b0 = blockIdx.x * SB;
  const u16* wwave = Wp + (size_t)(v * (NMT * 16) + lb) * KDIM + lq * 8;
  u16* alw = al + (size_t)v * F_LDS * 512;

  // one-time weight load: frag layout A[m=lane&15][k=quad*8+j]
  bf16x8 Areg[(F_REG > 0) ? F_REG : 1];
#pragma unroll
  for (int kc = 0; kc < NKC; ++kc)
#pragma unroll
    for (int mt = 0; mt < NMT; ++mt){
      const int idx = kc * NMT + mt;
      const u16* src = wwave + (size_t)(mt * 16) * KDIM + kc * 32;
      if (idx < F_REG)              Areg[idx] = *(const bf16x8*)src;
      else if (idx < F_REG + F_LDS) *(bf16x8*)&alw[(idx - F_REG) * 512 + l * 8] = *(const bf16x8*)src;
      // idx >= F_REG+F_LDS: stays in global (L1-resident; inline volatile read per use)
    }

  // xp lane base for this (slice, wave): chunk i at +i*CHS u16 (coalesced SB*64B/chunk)
  const u16* xpl = xp + ((size_t)blockIdx.x * NWAVE + v) * ((size_t)NCH * CHS) + lq * (SB * 8) + lb * 8;
  uint4 xq[NCH] = {};
  if (lb < SB){
#pragma unroll
    for (int i = 0; i < NCH; ++i) xq[i] = *(const uint4*)(xpl + (size_t)i * CHS);
  }

  for (int i = tid; i < 2 * BUFS; i += NWAVE * 64) hbuf[i] = 0;   // h(-1)=0 + dead b-slots
  float c[4];
#pragma unroll
  for (int j = 0; j < 4; j++) c[j] = 0.f;
  __syncthreads();

  for (int t = 0; t < T_N; ++t){
    const u16* hrd = hbuf + (size_t)(t & 1) * BUFS;
    u16*       hwr = hbuf + (size_t)((t & 1) ^ 1) * BUFS;

    if constexpr (NQ == 2){
      // ----- merged 2-phase path (enc) -----
      f32x4 acc[2][4];
#pragma unroll
      for (int ph = 0; ph < 2; ++ph)
#pragma unroll
        for (int g = 0; g < 4; ++g){
          const int qg = ph * 4 + g;
          const uint4 cx = xq[qg >> 1];
          const u32 w0 = (qg & 1) ? cx.z : cx.x;
          const u32 w1 = (qg & 1) ? cx.w : cx.y;
          acc[ph][g][0] = bflo(w0); acc[ph][g][1] = bfhi(w0);
          acc[ph][g][2] = bflo(w1); acc[ph][g][3] = bfhi(w1);
        }
      // reload ALL chunks with t+1 data (full step + barrier of lead)
      if (t + 1 < T_N && lb < SB){
#pragma unroll
        for (int ch = 0; ch < NCH; ++ch)
          xq[ch] = *(const uint4*)(xpl + XSTR_T + (size_t)ch * CHS);
      }
      __builtin_amdgcn_s_setprio(1);
#pragma unroll
      for (int kc = 0; kc < NKC; ++kc){
        const bf16x8 bh = *(const bf16x8*)&hrd[kc * 512 + l * 8];  // shared by both phases
#pragma unroll
        for (int ph = 0; ph < 2; ++ph)
#pragma unroll
          for (int g = 0; g < 4; ++g){
            const int idx = kc * NMT + g * NQ + ph;
            bf16x8 af;
            if (idx < F_REG)              af = Areg[idx];
            else if (idx < F_REG + F_LDS) af = *(const bf16x8*)&alw[(idx - F_REG) * 512 + l * 8];
            else {                         // L1-resident global tier; volatile defeats LICM
              const int mt = g * NQ + ph;
              u32v4 gw = *(const volatile u32v4*)(wwave + (size_t)(mt * 16) * KDIM + kc * 32);
              af = __builtin_bit_cast(bf16x8, gw);
            }
            acc[ph][g] = __builtin_amdgcn_mfma_f32_16x16x32_bf16(af, bh, acc[ph][g], 0, 0, 0);
          }
      }
      __builtin_amdgcn_s_setprio(0);
      if constexpr (SB == 8){
        // pack phase 1 (lanes lb<8) into lanes lb>=8; gates on 4 values/lane
        f32x4 comb[4];
#pragma unroll
        for (int g = 0; g < 4; ++g)
#pragma unroll
          for (int j = 0; j < 4; ++j)
            comb[g][j] = pack_dpp<0x118, 0xC>(acc[0][g][j], acc[1][g][j]);
        float hv[4];
#pragma unroll
        for (int j = 0; j < 4; ++j){
          float iv = sigm(comb[0][j]);
          float fv = sigm(comb[1][j]);
          float gv = tanh_f(comb[2][j]);
          float ov = sigm(comb[3][j]);
          float cc = fv * c[j] + iv * gv;
          c[j] = cc;
          hv[j] = ov * tanh_f(cc);
        }
        const int u0 = v * 32 + (lb >> 3) * 16 + lq * 4;
        const int widx = (u0 >> 5) * 512 + ((u0 >> 3) & 3) * 128 + (lb & 7) * 8 + (u0 & 7);
        uint2 hp; hp.x = cvtpk(hv[0], hv[1]); hp.y = cvtpk(hv[2], hv[3]);
        *(uint2*)&hwr[widx] = hp;
        __syncthreads();   // h(t) visible
        *(uint2*)(enc_out + (size_t)(t * 256 + b0 + (lb & 7)) * KDIM + u0) = hp;
      } else {
        // SB == 4: stage 1 pack phase1 (lanes 0..3) -> lanes 4..7
        f32x4 comb[4];
#pragma unroll
        for (int g = 0; g < 4; ++g)
#pragma unroll
          for (int j = 0; j < 4; ++j)
            comb[g][j] = pack_dpp<0x114, 0x2>(acc[0][g][j], acc[1][g][j]);
        // stage 2: pack j{2,3} (lanes 0..7) -> lanes 8..15; all 64 lanes live, 2 vals
        float fin[4][2];
#pragma unroll
        for (int g = 0; g < 4; ++g)
#pragma unroll
          for (int jj = 0; jj < 2; ++jj)
            fin[g][jj] = pack_dpp<0x118, 0xC>(comb[g][jj], comb[g][jj + 2]);
        float hv[2];
#pragma unroll
        for (int jj = 0; jj < 2; ++jj){
          float iv = sigm(fin[0][jj]);
          float fv = sigm(fin[1][jj]);
          float gv = tanh_f(fin[2][jj]);
          float ov = sigm(fin[3][jj]);
          float cc = fv * c[jj] + iv * gv;
          c[jj] = cc;
          hv[jj] = ov * tanh_f(cc);
        }
        // lane decode: b = lb&3, phase = (lb>>2)&1, j-half = lb>>3
        const int bq = lb & 3, ph = (lb >> 2) & 1, jh = lb >> 3;
        const int u0 = v * 32 + ph * 16 + lq * 4 + jh * 2;
        const int widx = (u0 >> 5) * 512 + ((u0 >> 3) & 3) * 128 + bq * 8 + (u0 & 7);
        const u32 hp = cvtpk(hv[0], hv[1]);
        *(u32*)&hwr[widx] = hp;
        __syncthreads();   // h(t) visible
        *(u32*)(enc_out + (size_t)(t * 256 + b0 + bq) * KDIM + u0) = hp;
      }
    } else {
      // ----- single-phase path (dec) -----
      float hv[2];
      int u0d;
      {
        const int q = 0;
        f32x4 acc[4];
#pragma unroll
        for (int g = 0; g < 4; ++g){
          const uint4 cx = xq[(q * 4 + g) >> 1];
          const u32 w0 = (g & 1) ? cx.z : cx.x;
          const u32 w1 = (g & 1) ? cx.w : cx.y;
          acc[g][0] = bflo(w0); acc[g][1] = bfhi(w0);
          acc[g][2] = bflo(w1); acc[g][3] = bfhi(w1);
        }
        if (t + 1 < T_N && lb < SB){
#pragma unroll
          for (int ch = 0; ch < NCH; ++ch)
            xq[ch] = *(const uint4*)(xpl + XSTR_T + (size_t)ch * CHS);
        }
        __builtin_amdgcn_s_setprio(1);
#pragma unroll
        for (int kc = 0; kc < NKC; ++kc){
          const bf16x8 bh = *(const bf16x8*)&hrd[kc * 512 + l * 8];
#pragma unroll
          for (int g = 0; g < 4; ++g){
            const int idx = kc * NMT + g * NQ + q;
            bf16x8 af;
            if (idx < F_REG)              af = Areg[idx];
            else if (idx < F_REG + F_LDS) af = *(const bf16x8*)&alw[(idx - F_REG) * 512 + l * 8];
            else {
              const int mt = g * NQ + q;
              u32v4 gw = *(const volatile u32v4*)(wwave + (size_t)(mt * 16) * KDIM + kc * 32);
              af = __builtin_bit_cast(bf16x8, gw);
            }
            acc[g] = __builtin_amdgcn_mfma_f32_16x16x32_bf16(af, bh, acc[g], 0, 0, 0);
          }
        }
        __builtin_amdgcn_s_setprio(0);
        // pack j{2,3} (lanes lb<8) into lanes lb>=8; gates 2 iters, all lanes live
        float fin[4][2];
#pragma unroll
        for (int g = 0; g < 4; ++g)
#pragma unroll
          for (int jj = 0; jj < 2; ++jj)
            fin[g][jj] = pack_dpp<0x118, 0xC>(acc[g][jj], acc[g][jj + 2]);
#pragma unroll
        for (int jj = 0; jj < 2; ++jj){
          float iv = sigm(fin[0][jj]);
          float fv = sigm(fin[1][jj]);
          float gv = tanh_f(fin[2][jj]);
          float ov = sigm(fin[3][jj]);
          float cc = fv * c[jj] + iv * gv;
          c[jj] = cc;
          hv[jj] = ov * tanh_f(cc);
        }
        // lane decode: b = lb&7, j-half = lb>>3
        u0d = v * 16 + lq * 4 + (lb >> 3) * 2;
        const int widx = (u0d >> 5) * 512 + ((u0d >> 3) & 3) * 128 + (lb & 7) * 8 + (u0d & 7);
        const u32 hp = cvtpk(hv[0], hv[1]);
        *(u32*)&hwr[widx] = hp;
      }
      __syncthreads();
      {
        float2 o2; o2.x = hv[0]; o2.y = hv[1];
        *(float2*)(out + ((size_t)(b0 + (lb & 7)) * T_N + t) * D_N + u0d) = o2;
      }
    }
    xpl += XSTR_T;
  }
}

extern "C" void kernel_launch(void* const* d_in, const int* in_sizes, int n_in,
                              void* d_out, int out_size, void* d_ws, size_t ws_size,
                              hipStream_t stream){
  const float* x    = (const float*)d_in[0];
  const float* eWih = (const float*)d_in[1];
  const float* eWhh = (const float*)d_in[2];
  const float* ebih = (const float*)d_in[3];
  const float* ebhh = (const float*)d_in[4];
  const float* dWih = (const float*)d_in[5];
  const float* dWhh = (const float*)d_in[6];
  const float* dbih = (const float*)d_in[7];
  const float* dbhh = (const float*)d_in[8];
  float* out = (float*)d_out;

  char* w = (char*)d_ws;
  size_t off = 0;
  auto carve = [&](size_t bytes) -> void* { void* p = w + off; off = (off + bytes + 255) & ~(size_t)255; return p; };
  u16*   xb    = (u16*)carve((size_t)B_N * T_N * D_N * 2);          // x in bf16, TRANSPOSED [T][B][D]
  u16*   WihEp = (u16*)carve((size_t)4 * H_N * D_N * 2);            // permuted enc Wih (UB=5,VB=3)
  u16*   WhhEp = (u16*)carve((size_t)4 * H_N * H_N * 2);            // permuted enc Whh (UB=5,VB=3)
  u16*   WihDp = (u16*)carve((size_t)4 * D_N * H_N * 2);            // permuted dec Wih (UB=4,VB=3)
  u16*   WhhDp = (u16*)carve((size_t)4 * D_N * D_N * 2);            // permuted dec Whh (UB=4,VB=3)
  float* bE    = (float*)carve((size_t)4 * H_N * 4);
  float* bD    = (float*)carve((size_t)4 * D_N * 4);
  u16*   xpE   = (u16*)carve((size_t)T_N * B_N * 4 * H_N * 2);      // swizzled [t][slice][v][ch][lq][bl][8]
  u16*   enc   = (u16*)carve((size_t)T_N * B_N * H_N * 2);          // encoded [T][B][H] bf16
  u16*   xpD   = (u16*)carve((size_t)T_N * B_N * 4 * D_N * 2);      // swizzled, dec
  (void)ws_size; (void)in_sizes; (void)n_in; (void)out_size;

  // fused prep: transpose-cvt (8192 blocks) + 4x permW (3072) + 2x permB
  hipLaunchKernelGGL(k_prep, dim3(8192 + 3072 + 2), dim3(256), 0, stream,
                     x, xb, eWih, WihEp, eWhh, WhhEp, dWih, WihDp, dWhh, WhhDp,
                     ebih, ebhh, bE, dbih, dbhh, bD);

  // enc x-proj: [65536,1024] = xb @ WihEp^T  (m = t*B+b); SB=4 layout
  hipLaunchKernelGGL((k_xproj<128, 5, 3, 4>),  dim3(1024, 16), dim3(256), 0, stream, xb,  WihEp, bE, xpE);
  // enc recurrence: SB=4, 64 wgs, 8 waves (2/SIMD), 44 reg + 18 LDS + 2 global frags
  // LDS: 2*8*512*2 + 8*18*1024 = 163840 B (exactly 160 KiB)
  hipLaunchKernelGGL((k_rec<256, 8, 4, 8, 8, 2, 44, 18, false>), dim3(64), dim3(512),
                     2 * 8 * 512 * 2 + 8 * 18 * 1024, stream, WhhEp, xpE, enc, (float*)nullptr);
  // dec x-proj: [65536,512] = enc @ WihDp^T (m = t*B+b); SB=8 layout
  hipLaunchKernelGGL((k_xproj<256, 4, 3, 8>), dim3(1024, 8),  dim3(256), 0, stream, enc, WihDp, bD, xpD);
  // dec recurrence: SB=8, 32 wgs, 8 waves (2/SIMD), all 16 frags in regs; fp32 out
  // LDS: 2*4*512*2 = 8192 B
  hipLaunchKernelGGL((k_rec<128, 8, 8, 4, 4, 1, 16, 0, true>),  dim3(32), dim3(512),
                     2 * 4 * 512 * 2, stream, WhhDp, xpD, (u16*)nullptr, out);
}